// Round 8
// baseline (683.950 us; speedup 1.0000x reference)
//
#include <hip/hip_runtime.h>
#include <hip/hip_bf16.h>

// GraphSAGE 3-layer: pool(64->64) -> pool(64->32) -> mean(32->32)
// R8: edge-parallel LDS-accumulate gathers (ds_max_u32 on raw bf16 bits /
// ds_add_f32) straight from coarse-sorted pairs -- kills csr_phase2, bucket[],
// row_ptr, and the per-node shuffle reductions (R7 gathers burned ~256
// wave-instr/node; edge-parallel is ~2.6/edge). Mean's 1/deg counted in LDS
// and folded into the sum flush. NOTE: assumes N <= 131072 (S=7, 128-node
// LDS tiles); harness N=100000.

typedef unsigned int uint;
typedef short short8 __attribute__((ext_vector_type(8)));
typedef float f32x4 __attribute__((ext_vector_type(4)));

__device__ __forceinline__ float bf2f(unsigned short h){
  return __uint_as_float(((uint)h) << 16);
}
__device__ __forceinline__ unsigned short f2bf(float f){
  uint u = __float_as_uint(f);
  u += 0x7fffu + ((u >> 16) & 1u);   // RNE
  return (unsigned short)(u >> 16);
}
__device__ __forceinline__ float lo16(uint u){ return __uint_as_float(u << 16); }
__device__ __forceinline__ float hi16(uint u){ return __uint_as_float(u & 0xffff0000u); }

// flags[0]=1 if float inputs bf16 else f32; flags[1]=1 if edge_index int64.
// Also zeroes chist (saves a memset launch).
__global__ void detect_kernel(const unsigned short* x, const int* ei, int* flags,
                              uint* chist){
  int lane = threadIdx.x;  // 64 threads
  for (int i = lane; i < 1024; i += 64) chist[i] = 0;
  int sane = 0;
  #pragma unroll
  for (int k = 0; k < 4; ++k){
    int e = (x[(lane * 4 + k) * 2] >> 7) & 0xff;
    sane += (e >= 118 && e <= 134);
  }
  #pragma unroll
  for (int off = 32; off; off >>= 1) sane += __shfl_down(sane, off, 64);
  unsigned long long b = __ballot(ei[1 + 2 * lane] != 0);
  if (lane == 0){ flags[0] = (sane >= 128); flags[1] = (b == 0ull); }
}

// ---------------- weight prep: bf16 + transpose to WT[C][K] ----------------
struct WConv {
  const void* src[13];
  int n[13], isbias[13], Cs[13], K[13], off[13];
};

__global__ void conv_w(WConv wc, unsigned short* wtbase, float* bbase,
                       const int* flags){
  int t = blockIdx.x, n = wc.n[t];
  int isbf = flags[0];
  if (wc.isbias[t]){
    float* d = bbase + wc.off[t];
    for (int i = threadIdx.x; i < n; i += blockDim.x)
      d[i] = isbf ? bf2f(((const unsigned short*)wc.src[t])[i])
                  : ((const float*)wc.src[t])[i];
  } else {
    unsigned short* d = wtbase + wc.off[t];
    int Cs = wc.Cs[t], K = wc.K[t], Cm = (1 << Cs) - 1;
    for (int i = threadIdx.x; i < n; i += blockDim.x){
      int k = i >> Cs, c = i & Cm;
      unsigned short v = isbf ? ((const unsigned short*)wc.src[t])[i]
                              : f2bf(((const float*)wc.src[t])[i]);
      d[c * K + k] = v;
    }
  }
}

__device__ __forceinline__ void load_edge(const void* ei, int E, int is64, int e,
                                          int& s, int& d){
  if (is64){
    const long long* p = (const long long*)ei;
    s = (int)p[e]; d = (int)p[E + e];
  } else {
    const int* p = (const int*)ei;
    s = p[e]; d = p[E + e];
  }
}
__device__ __forceinline__ int load_dst(const void* ei, int E, int is64, int e){
  return is64 ? (int)((const long long*)ei)[E + e] : ((const int*)ei)[E + e];
}

// ---------------- CSR build (coarse only) ----------------
#define CSR_CE 8192

// phase0: coarse histogram (dst>>S); reads dst halves only.
__global__ __launch_bounds__(256) void csr_phase0(
    const void* __restrict__ ei, const int* __restrict__ flags,
    uint* __restrict__ chist, int E, int N, int NB, int S)
{
  __shared__ uint h[1024];
  int is64 = flags[1], t = threadIdx.x;
  int e0 = blockIdx.x * CSR_CE;
  for (int i = t; i < 1024; i += 256) h[i] = 0;
  __syncthreads();
  #pragma unroll 4
  for (int it = 0; it < CSR_CE / 256; ++it){
    int e = e0 + it * 256 + t;
    if (e >= E) break;
    int d = load_dst(ei, E, is64, e);
    if ((unsigned)d >= (unsigned)N) continue;
    atomicAdd(&h[d >> S], 1u);
  }
  __syncthreads();
  for (int i = t; i < NB; i += 256){ uint c = h[i]; if (c) atomicAdd(chist + i, c); }
}

__global__ void csr_scan0(const uint* __restrict__ chist, int* __restrict__ cbase,
                          int* __restrict__ ccur, int NB)
{
  __shared__ int sm[256];
  int t = threadIdx.x;
  int g = (NB + 255) / 256;          // <= 4
  int vb = t * g, v[4], s = 0;
  for (int k = 0; k < g; ++k){
    int i = vb + k; int x = (i < NB) ? (int)chist[i] : 0; v[k] = x; s += x;
  }
  sm[t] = s; __syncthreads();
  for (int off = 1; off < 256; off <<= 1){
    int x = (t >= off) ? sm[t - off] : 0;
    __syncthreads(); sm[t] += x; __syncthreads();
  }
  int run = sm[t] - s;
  for (int k = 0; k < g; ++k){
    int i = vb + k;
    if (i < NB){ cbase[i] = run; ccur[i] = run; run += v[k]; }
  }
  if (t == 255) cbase[NB] = run;
}

// phase1: multisplit to coarse buckets; packed pair = (src<<S)|(dst&(2^S-1)).
__global__ __launch_bounds__(256) void csr_phase1(
    const void* __restrict__ ei, const int* __restrict__ flags,
    int* __restrict__ ccur, uint* __restrict__ pairs,
    int E, int N, int NB, int S)
{
  __shared__ uint hist[1024];
  __shared__ uint gbase[1024];
  int is64 = flags[1];
  int t = threadIdx.x;
  uint dmask = (1u << S) - 1u;
  int e0 = blockIdx.x * CSR_CE;
  for (int i = t; i < 1024; i += 256) hist[i] = 0;
  __syncthreads();
  #pragma unroll 4
  for (int it = 0; it < CSR_CE / 256; ++it){
    int e = e0 + it * 256 + t;
    if (e >= E) break;
    int s, d; load_edge(ei, E, is64, e, s, d);
    if ((unsigned)s >= (unsigned)N || (unsigned)d >= (unsigned)N) continue;
    atomicAdd(&hist[d >> S], 1u);
  }
  __syncthreads();
  for (int b = t; b < NB; b += 256){
    uint c = hist[b];
    if (c) gbase[b] = (uint)atomicAdd(&ccur[b], (int)c);
    hist[b] = 0;
  }
  __syncthreads();
  #pragma unroll 4
  for (int it = 0; it < CSR_CE / 256; ++it){
    int e = e0 + it * 256 + t;
    if (e >= E) break;
    int s, d; load_edge(ei, E, is64, e, s, d);
    if ((unsigned)s >= (unsigned)N || (unsigned)d >= (unsigned)N) continue;
    int b = d >> S;
    uint local = atomicAdd(&hist[b], 1u);
    pairs[gbase[b] + local] = ((uint)s << S) | ((uint)d & dmask);
  }
}

// ---------------- edge-parallel LDS-accumulate gathers ----------------
// Block = one coarse bucket (<=128 dst nodes). 8 lanes per edge, uint4 row
// loads, ds_max_u32 on raw u16 bf16 bits (values >= 0). Stride 65 breaks
// bank collisions (bank = (dl + 8i + k) % 32, dl random).
__global__ __launch_bounds__(256) void lds_gather_max64(
    const int* __restrict__ cbase, const uint* __restrict__ pairs,
    const unsigned short* __restrict__ m, unsigned short* __restrict__ agg,
    int N, int S)
{
  __shared__ uint acc[128 * 65];
  int b = blockIdx.x, t = threadIdx.x;
  for (int i = t; i < 128 * 65; i += 256) acc[i] = 0u;
  int n0 = b << S;
  int base = cbase[b], end = cbase[b + 1];
  uint dmask = (1u << S) - 1u;
  int fl = (t & 7) * 8;
  __syncthreads();
  for (int e = base + (t >> 3); e < end; e += 32){
    uint pr = pairs[e];
    int dl = (int)(pr & dmask);
    uint4 v = *(const uint4*)(m + ((size_t)(pr >> S)) * 64 + fl);
    uint* row = acc + dl * 65 + fl;
    atomicMax(row + 0, v.x & 0xffffu); atomicMax(row + 1, v.x >> 16);
    atomicMax(row + 2, v.y & 0xffffu); atomicMax(row + 3, v.y >> 16);
    atomicMax(row + 4, v.z & 0xffffu); atomicMax(row + 5, v.z >> 16);
    atomicMax(row + 6, v.w & 0xffffu); atomicMax(row + 7, v.w >> 16);
  }
  __syncthreads();
  int nl = t >> 1, part = (t & 1) * 32;
  int node = n0 + nl;
  if (node < N){
    const uint* row = acc + nl * 65 + part;
    uint pk[16];
    #pragma unroll
    for (int k = 0; k < 16; ++k) pk[k] = row[2 * k] | (row[2 * k + 1] << 16);
    uint4* dst = (uint4*)(agg + (size_t)node * 64 + part);
    dst[0] = make_uint4(pk[0], pk[1], pk[2], pk[3]);
    dst[1] = make_uint4(pk[4], pk[5], pk[6], pk[7]);
    dst[2] = make_uint4(pk[8], pk[9], pk[10], pk[11]);
    dst[3] = make_uint4(pk[12], pk[13], pk[14], pk[15]);
  }
}

// Sum: 4 lanes per edge (64B rows), ds_add_f32; per-edge count in LDS;
// 1/max(deg,1) folded into the bf16 flush (mean done here, not in the MM).
__global__ __launch_bounds__(256) void lds_gather_mean32(
    const int* __restrict__ cbase, const uint* __restrict__ pairs,
    const unsigned short* __restrict__ h2, unsigned short* __restrict__ ssum,
    int N, int S)
{
  __shared__ float sacc[128 * 33];
  __shared__ int scnt[128];
  int b = blockIdx.x, t = threadIdx.x;
  for (int i = t; i < 128 * 33; i += 256) sacc[i] = 0.f;
  if (t < 128) scnt[t] = 0;
  int n0 = b << S;
  int base = cbase[b], end = cbase[b + 1];
  uint dmask = (1u << S) - 1u;
  int fl = (t & 3) * 8;
  __syncthreads();
  for (int e = base + (t >> 2); e < end; e += 64){
    uint pr = pairs[e];
    int dl = (int)(pr & dmask);
    uint4 v = *(const uint4*)(h2 + ((size_t)(pr >> S)) * 32 + fl);
    float* row = sacc + dl * 33 + fl;
    atomicAdd(row + 0, lo16(v.x)); atomicAdd(row + 1, hi16(v.x));
    atomicAdd(row + 2, lo16(v.y)); atomicAdd(row + 3, hi16(v.y));
    atomicAdd(row + 4, lo16(v.z)); atomicAdd(row + 5, hi16(v.z));
    atomicAdd(row + 6, lo16(v.w)); atomicAdd(row + 7, hi16(v.w));
    if ((t & 3) == 0) atomicAdd(&scnt[dl], 1);
  }
  __syncthreads();
  int nl = t >> 1, part = (t & 1) * 16;
  int node = n0 + nl;
  if (node < N){
    float scale = 1.f / fmaxf((float)scnt[nl], 1.f);
    const float* row = sacc + nl * 33 + part;
    uint pk[8];
    #pragma unroll
    for (int k = 0; k < 8; ++k)
      pk[k] = (uint)f2bf(row[2 * k] * scale) |
              ((uint)f2bf(row[2 * k + 1] * scale) << 16);
    uint4* dst = (uint4*)(ssum + (size_t)node * 32 + part);
    dst[0] = make_uint4(pk[0], pk[1], pk[2], pk[3]);
    dst[1] = make_uint4(pk[4], pk[5], pk[6], pk[7]);
  }
}

// ---------------- MFMA dense transforms ----------------
__device__ __forceinline__ short8 ld_fragA_bf16(const unsigned short* A, int row,
                                                int K, int koff){
  return *(const short8*)(A + (size_t)row * K + koff);
}
__device__ __forceinline__ short8 ld_fragA_f32(const float* A, int row,
                                               int K, int koff){
  const float* q = A + (size_t)row * K + koff;
  float4 f0 = *(const float4*)q;
  float4 f1 = *(const float4*)(q + 4);
  short8 r;
  r[0] = (short)f2bf(f0.x); r[1] = (short)f2bf(f0.y);
  r[2] = (short)f2bf(f0.z); r[3] = (short)f2bf(f0.w);
  r[4] = (short)f2bf(f1.x); r[5] = (short)f2bf(f1.y);
  r[6] = (short)f2bf(f1.z); r[7] = (short)f2bf(f1.w);
  return r;
}
// relu bf16 with -0.0 (0x8000) squashed so raw-u16 max stays exact.
__device__ __forceinline__ unsigned short f2bf_relu(float f){
  return (unsigned short)(f2bf(fmaxf(f, 0.f)) & 0x7fff);
}

// KA in {32,64}; KB in {0,32,64}; CT = C/16 in {2,4}; AMODE: 0=bf16, 2=runtime.
template<int KA, int KB, int CT, bool RELU, bool OUTF32, int AMODE>
__global__ __launch_bounds__(256) void mfma_mm(
    const void* __restrict__ Av, const unsigned short* __restrict__ Bv,
    const unsigned short* __restrict__ WaT, const unsigned short* __restrict__ WbT,
    const float* __restrict__ bias,
    const int* __restrict__ flags, void* __restrict__ outv, int N)
{
  constexpr int C = CT * 16;
  int wid = threadIdx.x >> 6, lane = threadIdx.x & 63;
  int g = blockIdx.x * 4 + wid;
  int rt, ct;
  if constexpr (CT == 4){ rt = g >> 2; ct = g & 3; }
  else                  { rt = g >> 1; ct = g & 1; }
  int RT = (N + 15) >> 4;
  if (rt >= RT) return;
  int m = lane & 15, quad = lane >> 4;
  int row = rt * 16 + m;
  int rowc = row < N ? row : N - 1;
  int colbase = ct * 16;
  int koq = quad * 8;

  bool af32 = (AMODE == 2) && (flags[0] == 0);
  f32x4 accS = {0.f, 0.f, 0.f, 0.f};

  #pragma unroll
  for (int k0 = 0; k0 < KA; k0 += 32){
    short8 af = af32 ? ld_fragA_f32((const float*)Av, rowc, KA, k0 + koq)
                     : ld_fragA_bf16((const unsigned short*)Av, rowc, KA, k0 + koq);
    short8 wf = *(const short8*)(WaT + (size_t)(colbase + m) * KA + k0 + koq);
    accS = __builtin_amdgcn_mfma_f32_16x16x32_bf16(af, wf, accS, 0, 0, 0);
  }
  if constexpr (KB > 0){
    #pragma unroll
    for (int k0 = 0; k0 < KB; k0 += 32){
      short8 bf = ld_fragA_bf16(Bv, rowc, KB, k0 + koq);
      short8 wf = *(const short8*)(WbT + (size_t)(colbase + m) * KB + k0 + koq);
      accS = __builtin_amdgcn_mfma_f32_16x16x32_bf16(bf, wf, accS, 0, 0, 0);
    }
  }
  float bv = bias[colbase + m];
  #pragma unroll
  for (int r = 0; r < 4; ++r){
    int orow = rt * 16 + quad * 4 + r;
    if (orow >= N) continue;
    float v = accS[r] + bv;
    if constexpr (OUTF32){
      if constexpr (RELU) v = fmaxf(v, 0.f);
      ((float*)outv)[(size_t)orow * C + colbase + m] = v;
    } else {
      unsigned short o;
      if constexpr (RELU) o = f2bf_relu(v);
      else                o = f2bf(v);
      ((unsigned short*)outv)[(size_t)orow * C + colbase + m] = o;
    }
  }
}

// Fused: h1 = relu(A@WaT^T + B@WbT^T + b1), then mbuf2 = relu(h1@WcT^T + b2p).
// Block = 4 waves = one 16-row tile; h1 tile round-trips through LDS.
template<int AMODE>
__global__ __launch_bounds__(256) void mfma_mm_fused(
    const void* __restrict__ Av, const unsigned short* __restrict__ Bv,
    const unsigned short* __restrict__ WaT, const unsigned short* __restrict__ WbT,
    const float* __restrict__ bias1,
    const unsigned short* __restrict__ WcT, const float* __restrict__ bias2,
    const int* __restrict__ flags,
    unsigned short* __restrict__ out1, unsigned short* __restrict__ out2, int N)
{
  constexpr int K = 64, C = 64, LDH = 72;
  __shared__ unsigned short hl[16 * LDH];
  int wid = threadIdx.x >> 6, lane = threadIdx.x & 63;
  int rt = blockIdx.x;
  int m = lane & 15, quad = lane >> 4;
  int row = rt * 16 + m;
  int rowc = row < N ? row : N - 1;
  int colbase = wid * 16;
  int koq = quad * 8;
  bool af32 = (AMODE == 2) && (flags[0] == 0);

  f32x4 acc = {0.f, 0.f, 0.f, 0.f};
  #pragma unroll
  for (int k0 = 0; k0 < K; k0 += 32){
    short8 af = af32 ? ld_fragA_f32((const float*)Av, rowc, K, k0 + koq)
                     : ld_fragA_bf16((const unsigned short*)Av, rowc, K, k0 + koq);
    short8 wf = *(const short8*)(WaT + (size_t)(colbase + m) * K + k0 + koq);
    acc = __builtin_amdgcn_mfma_f32_16x16x32_bf16(af, wf, acc, 0, 0, 0);
    short8 bf = ld_fragA_bf16(Bv, rowc, K, k0 + koq);
    short8 wg = *(const short8*)(WbT + (size_t)(colbase + m) * K + k0 + koq);
    acc = __builtin_amdgcn_mfma_f32_16x16x32_bf16(bf, wg, acc, 0, 0, 0);
  }
  float bv = bias1[colbase + m];
  #pragma unroll
  for (int r = 0; r < 4; ++r){
    int rl = quad * 4 + r;
    int orow = rt * 16 + rl;
    unsigned short hb = f2bf_relu(acc[r] + bv);
    hl[rl * LDH + colbase + m] = hb;
    if (orow < N) out1[(size_t)orow * C + colbase + m] = hb;
  }
  __syncthreads();
  f32x4 acc2 = {0.f, 0.f, 0.f, 0.f};
  #pragma unroll
  for (int k0 = 0; k0 < K; k0 += 32){
    short8 af = *(const short8*)(hl + m * LDH + k0 + koq);
    short8 wf = *(const short8*)(WcT + (size_t)(colbase + m) * K + k0 + koq);
    acc2 = __builtin_amdgcn_mfma_f32_16x16x32_bf16(af, wf, acc2, 0, 0, 0);
  }
  float b2v = bias2[colbase + m];
  #pragma unroll
  for (int r = 0; r < 4; ++r){
    int orow = rt * 16 + quad * 4 + r;
    if (orow < N)
      out2[(size_t)orow * C + colbase + m] = f2bf_relu(acc2[r] + b2v);
  }
}

static inline char* align256(char* p){
  return (char*)(((uintptr_t)p + 255) & ~(uintptr_t)255);
}

extern "C" void kernel_launch(void* const* d_in, const int* in_sizes, int n_in,
                              void* d_out, int out_size, void* d_ws, size_t ws_size,
                              hipStream_t stream)
{
  const void* x = d_in[0];
  const void* ei = d_in[1];
  int N = in_sizes[0] / 64;   // 100000
  int E = in_sizes[1] / 2;    // 1600000

  char* ws = (char*)d_ws;
  unsigned short* wtbase = (unsigned short*)ws;     // 22528 ushorts (45KB)
  float* bbase = (float*)(ws + 65536);              // 256 floats
  int* flags = (int*)(ws + 131072 - 256);

  const int S = 7;
  int NB = (N + 127) >> 7;    // <= 1024 for N <= 131072 (harness N=100000)

  char* p = ws + 131072;
  uint* chist  = (uint*)p; p = align256(p + 4352);
  int* cbase   = (int*)p; p = align256(p + 4352);
  int* ccur    = (int*)p; p = align256(p + 4352);
  uint* pairs  = (uint*)p; p = align256(p + (size_t)E * 4);   // live all 3 layers
  char* P = p;  p = align256(p + (size_t)N * 64 * 2);   // mbuf / h2
  char* Q = p;  p = align256(p + (size_t)N * 64 * 2);   // aggb / ssum
  char* R = p;  p = align256(p + (size_t)N * 64 * 2);   // h1
  unsigned short* mbuf = (unsigned short*)P;
  unsigned short* h2   = (unsigned short*)P;   // after mbuf dead
  unsigned short* aggb = (unsigned short*)Q;
  unsigned short* ssum = (unsigned short*)Q;   // after aggb dead
  unsigned short* h1   = (unsigned short*)R;

  hipLaunchKernelGGL(detect_kernel, dim3(1), dim3(64), 0, stream,
                     (const unsigned short*)x, (const int*)ei, flags, chist);

  WConv wc;
  {
    const int widx[13] = {2, 3, 4, 5, 6, 7, 8, 9, 10, 11, 12, 13, 14};
    const int isb[13]  = {0, 1, 0, 0, 1, 0, 1, 0, 0, 1, 0, 0, 1};
    const int Cs[13]   = {6, 0, 6, 6, 0, 6, 0, 5, 5, 0, 5, 5, 0};
    const int Kk[13]   = {64, 0, 64, 64, 0, 64, 0, 64, 64, 0, 32, 32, 0};
    const int off[13]  = {0, 0, 4096, 8192, 64, 12288, 128, 16384, 18432, 192,
                          20480, 21504, 224};
    for (int i = 0; i < 13; ++i){
      wc.src[i] = d_in[widx[i]]; wc.n[i] = in_sizes[widx[i]];
      wc.isbias[i] = isb[i]; wc.Cs[i] = Cs[i]; wc.K[i] = Kk[i]; wc.off[i] = off[i];
    }
  }
  hipLaunchKernelGGL(conv_w, dim3(13), dim3(256), 0, stream, wc, wtbase, bbase, flags);
  unsigned short* W1pT = wtbase + 0;     unsigned short* W1sT = wtbase + 4096;
  unsigned short* W1nT = wtbase + 8192;  unsigned short* W2pT = wtbase + 12288;
  unsigned short* W2sT = wtbase + 16384; unsigned short* W2nT = wtbase + 18432;
  unsigned short* W3sT = wtbase + 20480; unsigned short* W3nT = wtbase + 21504;
  float* b1p = bbase + 0;  float* b1 = bbase + 64; float* b2p = bbase + 128;
  float* b2 = bbase + 192; float* b3 = bbase + 224;

  // ---- coarse CSR build (no exact per-node sort needed) ----
  int nP = (E + CSR_CE - 1) / CSR_CE;
  csr_phase0<<<nP, 256, 0, stream>>>(ei, flags, chist, E, N, NB, S);
  csr_scan0<<<1, 256, 0, stream>>>(chist, cbase, ccur, NB);
  csr_phase1<<<nP, 256, 0, stream>>>(ei, flags, ccur, pairs, E, N, NB, S);

  int RT = (N + 15) / 16;
  int gc2 = (RT * 2 + 3) / 4;   // CT=2 kernels

  // ---- layer 1 (pool 64->64, relu) + layer-2 pool transform fused ----
  mfma_mm<64,0,4,true,false,2><<<RT,256,0,stream>>>(
      x, nullptr, W1pT, nullptr, b1p, flags, mbuf, N);
  lds_gather_max64<<<NB,256,0,stream>>>(cbase, pairs, mbuf, aggb, N, S);
  mfma_mm_fused<2><<<RT,256,0,stream>>>(
      x, aggb, W1sT, W1nT, b1, W2pT, b2p, flags, h1, mbuf, N);

  // ---- layer 2 (pool 64->32) ----
  lds_gather_max64<<<NB,256,0,stream>>>(cbase, pairs, mbuf, aggb, N, S);
  mfma_mm<64,64,2,false,false,0><<<gc2,256,0,stream>>>(
      h1, aggb, W2sT, W2nT, b2, flags, h2, N);

  // ---- layer 3 (mean 32->32, f32 out; 1/deg folded into gather flush) ----
  lds_gather_mean32<<<NB,256,0,stream>>>(cbase, pairs, h2, ssum, N, S);
  mfma_mm<32,32,2,false,true,0><<<gc2,256,0,stream>>>(
      h2, ssum, W3sT, W3nT, b3, flags, d_out, N);
}

// Round 9
// 344.100 us; speedup vs baseline: 1.9877x; 1.9877x over previous
//
#include <hip/hip_runtime.h>
#include <hip/hip_bf16.h>

// GraphSAGE 3-layer: pool(64->64) -> pool(64->32) -> mean(32->32)
// R9: revert R8's edge-parallel LDS-atomic gathers (DS atomics lane-serialize:
// 343us, VALUBusy 1%). Back to R7 shuffle-gather structure + NEW: two nodes
// per wave with interleaved load streams (2x memory-level parallelism at
// deg~16 where each node has only ~1 load-iteration in flight).

typedef unsigned int uint;
typedef short short8 __attribute__((ext_vector_type(8)));
typedef float f32x4 __attribute__((ext_vector_type(4)));
typedef float f32x2 __attribute__((ext_vector_type(2)));
typedef unsigned short u16x8 __attribute__((ext_vector_type(8)));

__device__ __forceinline__ float bf2f(unsigned short h){
  return __uint_as_float(((uint)h) << 16);
}
__device__ __forceinline__ unsigned short f2bf(float f){
  uint u = __float_as_uint(f);
  u += 0x7fffu + ((u >> 16) & 1u);   // RNE
  return (unsigned short)(u >> 16);
}
__device__ __forceinline__ float lo16(uint u){ return __uint_as_float(u << 16); }
__device__ __forceinline__ float hi16(uint u){ return __uint_as_float(u & 0xffff0000u); }

__device__ __forceinline__ uint4 pkmax4(uint4 a, uint4 b){
  u16x8 x = __builtin_bit_cast(u16x8, a);
  u16x8 y = __builtin_bit_cast(u16x8, b);
  return __builtin_bit_cast(uint4, __builtin_elementwise_max(x, y));
}
__device__ __forceinline__ uint4 shflx4(uint4 a, int off){
  uint4 r;
  r.x = (uint)__shfl_xor((int)a.x, off, 64);
  r.y = (uint)__shfl_xor((int)a.y, off, 64);
  r.z = (uint)__shfl_xor((int)a.z, off, 64);
  r.w = (uint)__shfl_xor((int)a.w, off, 64);
  return r;
}

// flags[0]=1 if float inputs bf16 else f32; flags[1]=1 if edge_index int64.
// Also zeroes chist (saves a memset launch).
__global__ void detect_kernel(const unsigned short* x, const int* ei, int* flags,
                              uint* chist){
  int lane = threadIdx.x;  // 64 threads
  for (int i = lane; i < 1024; i += 64) chist[i] = 0;
  int sane = 0;
  #pragma unroll
  for (int k = 0; k < 4; ++k){
    int e = (x[(lane * 4 + k) * 2] >> 7) & 0xff;
    sane += (e >= 118 && e <= 134);
  }
  #pragma unroll
  for (int off = 32; off; off >>= 1) sane += __shfl_down(sane, off, 64);
  unsigned long long b = __ballot(ei[1 + 2 * lane] != 0);
  if (lane == 0){ flags[0] = (sane >= 128); flags[1] = (b == 0ull); }
}

// ---------------- weight prep: bf16 + transpose to WT[C][K] ----------------
struct WConv {
  const void* src[13];
  int n[13], isbias[13], Cs[13], K[13], off[13];
};

__global__ void conv_w(WConv wc, unsigned short* wtbase, float* bbase,
                       const int* flags){
  int t = blockIdx.x, n = wc.n[t];
  int isbf = flags[0];
  if (wc.isbias[t]){
    float* d = bbase + wc.off[t];
    for (int i = threadIdx.x; i < n; i += blockDim.x)
      d[i] = isbf ? bf2f(((const unsigned short*)wc.src[t])[i])
                  : ((const float*)wc.src[t])[i];
  } else {
    unsigned short* d = wtbase + wc.off[t];
    int Cs = wc.Cs[t], K = wc.K[t], Cm = (1 << Cs) - 1;
    for (int i = threadIdx.x; i < n; i += blockDim.x){
      int k = i >> Cs, c = i & Cm;
      unsigned short v = isbf ? ((const unsigned short*)wc.src[t])[i]
                              : f2bf(((const float*)wc.src[t])[i]);
      d[c * K + k] = v;
    }
  }
}

__device__ __forceinline__ void load_edge(const void* ei, int E, int is64, int e,
                                          int& s, int& d){
  if (is64){
    const long long* p = (const long long*)ei;
    s = (int)p[e]; d = (int)p[E + e];
  } else {
    const int* p = (const int*)ei;
    s = p[e]; d = p[E + e];
  }
}

// ---------------- CSR build ----------------
#define CSR_CE 8192

__global__ __launch_bounds__(256) void csr_phase0(
    const void* __restrict__ ei, const int* __restrict__ flags,
    uint* __restrict__ chist, int E, int N, int NB, int S)
{
  __shared__ uint h[1024];
  int is64 = flags[1], t = threadIdx.x;
  int e0 = blockIdx.x * CSR_CE;
  for (int i = t; i < 1024; i += 256) h[i] = 0;
  __syncthreads();
  #pragma unroll 4
  for (int it = 0; it < CSR_CE / 256; ++it){
    int e = e0 + it * 256 + t;
    if (e >= E) break;
    int s, d; load_edge(ei, E, is64, e, s, d);
    if ((unsigned)s >= (unsigned)N || (unsigned)d >= (unsigned)N) continue;
    atomicAdd(&h[d >> S], 1u);
  }
  __syncthreads();
  for (int i = t; i < NB; i += 256){ uint c = h[i]; if (c) atomicAdd(chist + i, c); }
}

__global__ void csr_scan0(const uint* __restrict__ chist, int* __restrict__ cbase,
                          int* __restrict__ ccur, int* __restrict__ rowptrN, int NB)
{
  __shared__ int sm[256];
  int t = threadIdx.x;
  int g = (NB + 255) / 256;          // <= 4
  int vb = t * g, v[4], s = 0;
  for (int k = 0; k < g; ++k){
    int i = vb + k; int x = (i < NB) ? (int)chist[i] : 0; v[k] = x; s += x;
  }
  sm[t] = s; __syncthreads();
  for (int off = 1; off < 256; off <<= 1){
    int x = (t >= off) ? sm[t - off] : 0;
    __syncthreads(); sm[t] += x; __syncthreads();
  }
  int run = sm[t] - s;
  for (int k = 0; k < g; ++k){
    int i = vb + k;
    if (i < NB){ cbase[i] = run; ccur[i] = run; run += v[k]; }
  }
  if (t == 255){ cbase[NB] = run; *rowptrN = run; }
}

// phase1: multisplit to coarse buckets; packed pair = (src<<S)|(dst&(2^S-1)).
__global__ __launch_bounds__(256) void csr_phase1(
    const void* __restrict__ ei, const int* __restrict__ flags,
    int* __restrict__ ccur, uint* __restrict__ pairs,
    int E, int N, int NB, int S)
{
  __shared__ uint hist[1024];
  __shared__ uint gbase[1024];
  int is64 = flags[1];
  int t = threadIdx.x;
  uint dmask = (1u << S) - 1u;
  int e0 = blockIdx.x * CSR_CE;
  for (int i = t; i < 1024; i += 256) hist[i] = 0;
  __syncthreads();
  #pragma unroll 4
  for (int it = 0; it < CSR_CE / 256; ++it){
    int e = e0 + it * 256 + t;
    if (e >= E) break;
    int s, d; load_edge(ei, E, is64, e, s, d);
    if ((unsigned)s >= (unsigned)N || (unsigned)d >= (unsigned)N) continue;
    atomicAdd(&hist[d >> S], 1u);
  }
  __syncthreads();
  for (int b = t; b < NB; b += 256){
    uint c = hist[b];
    if (c) gbase[b] = (uint)atomicAdd(&ccur[b], (int)c);
    hist[b] = 0;
  }
  __syncthreads();
  #pragma unroll 4
  for (int it = 0; it < CSR_CE / 256; ++it){
    int e = e0 + it * 256 + t;
    if (e >= E) break;
    int s, d; load_edge(ei, E, is64, e, s, d);
    if ((unsigned)s >= (unsigned)N || (unsigned)d >= (unsigned)N) continue;
    int b = d >> S;
    uint local = atomicAdd(&hist[b], 1u);
    pairs[gbase[b] + local] = ((uint)s << S) | ((uint)d & dmask);
  }
}

// phase2: per-bucket hist+scan in LDS -> row_ptr slice, exact placement.
#define P2_CAP 6144
__global__ __launch_bounds__(256) void csr_phase2(
    const int* __restrict__ cbase, const uint* __restrict__ pairs,
    int* __restrict__ bucket, int* __restrict__ row_ptr, int N, int S)
{
  __shared__ int lbuf[P2_CAP];
  __shared__ int cur[1024];
  __shared__ int sm[256];
  int b = blockIdx.x, t = threadIdx.x;
  uint dmask = (1u << S) - 1u;
  int n0 = b << S;
  int n1 = n0 + (1 << S); if (n1 > N) n1 = N;
  int nn = n1 - n0;
  int base = cbase[b], end = cbase[b + 1], cnt = end - base;

  for (int i = t; i < nn; i += 256) cur[i] = 0;
  __syncthreads();
  for (int j = base + t; j < end; j += 256)
    atomicAdd(&cur[(int)(pairs[j] & dmask)], 1);
  __syncthreads();
  int g = (nn + 255) / 256, vb = t * g, v[4], s = 0;
  for (int k = 0; k < g; ++k){
    int i = vb + k; int x = (i < nn) ? cur[i] : 0; v[k] = x; s += x;
  }
  sm[t] = s; __syncthreads();
  for (int off = 1; off < 256; off <<= 1){
    int x = (t >= off) ? sm[t - off] : 0;
    __syncthreads(); sm[t] += x; __syncthreads();
  }
  int run = sm[t] - s;
  for (int k = 0; k < g; ++k){
    int i = vb + k;
    if (i < nn){ row_ptr[n0 + i] = base + run; cur[i] = run; run += v[k]; }
  }
  __syncthreads();
  if (cnt <= 0) return;
  if (cnt <= P2_CAP){
    for (int j = base + t; j < end; j += 256){
      uint pr = pairs[j];
      int pos = atomicAdd(&cur[(int)(pr & dmask)], 1);
      lbuf[pos] = (int)(pr >> S);
    }
    __syncthreads();
    for (int i = t; i < cnt; i += 256) bucket[base + i] = lbuf[i];
  } else {
    for (int j = base + t; j < end; j += 256){
      uint pr = pairs[j];
      int pos = atomicAdd(&cur[(int)(pr & dmask)], 1);
      bucket[base + pos] = (int)(pr >> S);
    }
  }
}

// ---------------- gather-reduce: two nodes per wave, interleaved ----------------
// Nodes (2w, 2w+1). fg8=(lane&7)*8 features (uint4=16B); rowsel=lane>>3 ->
// 8 rows/load/stream; both streams' loads hoisted for MLP. Packed u16 max on
// raw bf16 bits (post-relu >= 0, -0.0 squashed by producers).
__global__ __launch_bounds__(256) void gather_max64(
    const int* __restrict__ row_ptr, const int* __restrict__ bucket,
    const unsigned short* __restrict__ m, unsigned short* __restrict__ agg, int N)
{
  int wave = (int)((blockIdx.x * 256u + threadIdx.x) >> 6);
  int lane = threadIdx.x & 63;
  int nodeA = wave * 2, nodeB = nodeA + 1;
  if (nodeA >= N) return;
  bool hasB = nodeB < N;
  int rsA = row_ptr[nodeA], reA = row_ptr[nodeA + 1];
  int cntA = reA - rsA;
  int rsB = reA, cntB = hasB ? (row_ptr[nodeB + 1] - reA) : 0;
  int fg8 = (lane & 7) * 8, rowsel = lane >> 3;
  uint4 accA = {0u,0u,0u,0u}, accB = {0u,0u,0u,0u};
  int cmax = max(cntA, cntB);
  for (int c0 = 0; c0 < cmax; c0 += 64){
    int chA = min(cntA - c0, 64);            // may be <= 0
    int chB = min(cntB - c0, 64);
    int bvA = (lane < chA) ? bucket[rsA + c0 + lane] : 0;
    int bvB = (lane < chB) ? bucket[rsB + c0 + lane] : 0;
    int it = (max(chA, chB) + 7) >> 3;
    for (int k = 0; k < it; ++k){
      int j = k * 8 + rowsel;                // < 64 always
      int sA = __shfl(bvA, j, 64);
      int sB = __shfl(bvB, j, 64);
      uint4 vA = *(const uint4*)(m + (size_t)sA * 64 + fg8);
      uint4 vB = *(const uint4*)(m + (size_t)sB * 64 + fg8);
      if (j < chA) accA = pkmax4(accA, vA);
      if (j < chB) accB = pkmax4(accB, vB);
    }
  }
  #pragma unroll
  for (int off = 8; off <= 32; off <<= 1){
    accA = pkmax4(accA, shflx4(accA, off));
    accB = pkmax4(accB, shflx4(accB, off));
  }
  if (lane < 8){
    *(uint4*)(agg + (size_t)nodeA * 64 + fg8) = accA;
  } else if (lane < 16 && hasB){
    *(uint4*)(agg + (size_t)nodeB * 64 + (lane & 7) * 8) = accB;
  }
}

// Two nodes per wave; 64B rows. fg8=(lane&3)*8; rowsel=lane>>2 -> 16 rows/load.
__device__ __forceinline__ f32x2 b2lo(uint u){
  f32x2 r; r.x = lo16(u); r.y = hi16(u); return r;
}
__global__ __launch_bounds__(256) void gather_sum32(
    const int* __restrict__ row_ptr, const int* __restrict__ bucket,
    const unsigned short* __restrict__ h2, unsigned short* __restrict__ ssum, int N)
{
  int wave = (int)((blockIdx.x * 256u + threadIdx.x) >> 6);
  int lane = threadIdx.x & 63;
  int nodeA = wave * 2, nodeB = nodeA + 1;
  if (nodeA >= N) return;
  bool hasB = nodeB < N;
  int rsA = row_ptr[nodeA], reA = row_ptr[nodeA + 1];
  int cntA = reA - rsA;
  int rsB = reA, cntB = hasB ? (row_ptr[nodeB + 1] - reA) : 0;
  int fg8 = (lane & 3) * 8, rowsel = lane >> 2;
  f32x2 aA0 = {0.f,0.f}, aA1 = {0.f,0.f}, aA2 = {0.f,0.f}, aA3 = {0.f,0.f};
  f32x2 aB0 = {0.f,0.f}, aB1 = {0.f,0.f}, aB2 = {0.f,0.f}, aB3 = {0.f,0.f};
  int cmax = max(cntA, cntB);
  for (int c0 = 0; c0 < cmax; c0 += 64){
    int chA = min(cntA - c0, 64);
    int chB = min(cntB - c0, 64);
    int bvA = (lane < chA) ? bucket[rsA + c0 + lane] : 0;
    int bvB = (lane < chB) ? bucket[rsB + c0 + lane] : 0;
    int it = (max(chA, chB) + 15) >> 4;
    for (int k = 0; k < it; ++k){
      int j = k * 16 + rowsel;               // < 64 always
      int sA = __shfl(bvA, j, 64);
      int sB = __shfl(bvB, j, 64);
      uint4 vA = *(const uint4*)(h2 + (size_t)sA * 32 + fg8);
      uint4 vB = *(const uint4*)(h2 + (size_t)sB * 32 + fg8);
      if (j < chA){
        aA0 += b2lo(vA.x); aA1 += b2lo(vA.y); aA2 += b2lo(vA.z); aA3 += b2lo(vA.w);
      }
      if (j < chB){
        aB0 += b2lo(vB.x); aB1 += b2lo(vB.y); aB2 += b2lo(vB.z); aB3 += b2lo(vB.w);
      }
    }
  }
  #pragma unroll
  for (int off = 4; off <= 32; off <<= 1){
    aA0.x += __shfl_xor(aA0.x, off, 64); aA0.y += __shfl_xor(aA0.y, off, 64);
    aA1.x += __shfl_xor(aA1.x, off, 64); aA1.y += __shfl_xor(aA1.y, off, 64);
    aA2.x += __shfl_xor(aA2.x, off, 64); aA2.y += __shfl_xor(aA2.y, off, 64);
    aA3.x += __shfl_xor(aA3.x, off, 64); aA3.y += __shfl_xor(aA3.y, off, 64);
    aB0.x += __shfl_xor(aB0.x, off, 64); aB0.y += __shfl_xor(aB0.y, off, 64);
    aB1.x += __shfl_xor(aB1.x, off, 64); aB1.y += __shfl_xor(aB1.y, off, 64);
    aB2.x += __shfl_xor(aB2.x, off, 64); aB2.y += __shfl_xor(aB2.y, off, 64);
    aB3.x += __shfl_xor(aB3.x, off, 64); aB3.y += __shfl_xor(aB3.y, off, 64);
  }
  if (lane < 4){
    uint4 pk;
    pk.x = (uint)f2bf(aA0.x) | ((uint)f2bf(aA0.y) << 16);
    pk.y = (uint)f2bf(aA1.x) | ((uint)f2bf(aA1.y) << 16);
    pk.z = (uint)f2bf(aA2.x) | ((uint)f2bf(aA2.y) << 16);
    pk.w = (uint)f2bf(aA3.x) | ((uint)f2bf(aA3.y) << 16);
    *(uint4*)(ssum + (size_t)nodeA * 32 + fg8) = pk;
  } else if (lane < 8 && hasB){
    uint4 pk;
    pk.x = (uint)f2bf(aB0.x) | ((uint)f2bf(aB0.y) << 16);
    pk.y = (uint)f2bf(aB1.x) | ((uint)f2bf(aB1.y) << 16);
    pk.z = (uint)f2bf(aB2.x) | ((uint)f2bf(aB2.y) << 16);
    pk.w = (uint)f2bf(aB3.x) | ((uint)f2bf(aB3.y) << 16);
    *(uint4*)(ssum + (size_t)nodeB * 32 + (lane & 3) * 8) = pk;
  }
}

// ---------------- MFMA dense transforms ----------------
__device__ __forceinline__ short8 ld_fragA_bf16(const unsigned short* A, int row,
                                                int K, int koff){
  return *(const short8*)(A + (size_t)row * K + koff);
}
__device__ __forceinline__ short8 ld_fragA_f32(const float* A, int row,
                                               int K, int koff){
  const float* q = A + (size_t)row * K + koff;
  float4 f0 = *(const float4*)q;
  float4 f1 = *(const float4*)(q + 4);
  short8 r;
  r[0] = (short)f2bf(f0.x); r[1] = (short)f2bf(f0.y);
  r[2] = (short)f2bf(f0.z); r[3] = (short)f2bf(f0.w);
  r[4] = (short)f2bf(f1.x); r[5] = (short)f2bf(f1.y);
  r[6] = (short)f2bf(f1.z); r[7] = (short)f2bf(f1.w);
  return r;
}
// relu bf16 with -0.0 (0x8000) squashed so packed-u16 max stays exact.
__device__ __forceinline__ unsigned short f2bf_relu(float f){
  return (unsigned short)(f2bf(fmaxf(f, 0.f)) & 0x7fff);
}

// KA in {32,64}; KB in {0,32,64}; CT = C/16 in {2,4}; AMODE: 0=bf16, 2=runtime.
template<int KA, int KB, int CT, bool RELU, bool MEAN, bool OUTF32, int AMODE>
__global__ __launch_bounds__(256) void mfma_mm(
    const void* __restrict__ Av, const unsigned short* __restrict__ Bv,
    const unsigned short* __restrict__ WaT, const unsigned short* __restrict__ WbT,
    const float* __restrict__ bias, const int* __restrict__ row_ptr,
    const int* __restrict__ flags, void* __restrict__ outv, int N)
{
  constexpr int C = CT * 16;
  int wid = threadIdx.x >> 6, lane = threadIdx.x & 63;
  int g = blockIdx.x * 4 + wid;
  int rt, ct;
  if constexpr (CT == 4){ rt = g >> 2; ct = g & 3; }
  else                  { rt = g >> 1; ct = g & 1; }
  int RT = (N + 15) >> 4;
  if (rt >= RT) return;
  int m = lane & 15, quad = lane >> 4;
  int row = rt * 16 + m;
  int rowc = row < N ? row : N - 1;
  int colbase = ct * 16;
  int koq = quad * 8;

  bool af32 = (AMODE == 2) && (flags[0] == 0);
  f32x4 accS = {0.f, 0.f, 0.f, 0.f};
  f32x4 accA = {0.f, 0.f, 0.f, 0.f};

  #pragma unroll
  for (int k0 = 0; k0 < KA; k0 += 32){
    short8 af = af32 ? ld_fragA_f32((const float*)Av, rowc, KA, k0 + koq)
                     : ld_fragA_bf16((const unsigned short*)Av, rowc, KA, k0 + koq);
    short8 wf = *(const short8*)(WaT + (size_t)(colbase + m) * KA + k0 + koq);
    accS = __builtin_amdgcn_mfma_f32_16x16x32_bf16(af, wf, accS, 0, 0, 0);
  }
  if constexpr (KB > 0){
    #pragma unroll
    for (int k0 = 0; k0 < KB; k0 += 32){
      short8 bf = ld_fragA_bf16(Bv, rowc, KB, k0 + koq);
      short8 wf = *(const short8*)(WbT + (size_t)(colbase + m) * KB + k0 + koq);
      if constexpr (MEAN)
        accA = __builtin_amdgcn_mfma_f32_16x16x32_bf16(bf, wf, accA, 0, 0, 0);
      else
        accS = __builtin_amdgcn_mfma_f32_16x16x32_bf16(bf, wf, accS, 0, 0, 0);
    }
  }
  float bv = bias[colbase + m];
  #pragma unroll
  for (int r = 0; r < 4; ++r){
    int orow = rt * 16 + quad * 4 + r;
    if (orow >= N) continue;
    float v = accS[r] + bv;
    if constexpr (MEAN){
      int dg = row_ptr[orow + 1] - row_ptr[orow];
      v += accA[r] * (1.f / fmaxf((float)dg, 1.f));
    }
    if constexpr (OUTF32){
      if constexpr (RELU) v = fmaxf(v, 0.f);
      ((float*)outv)[(size_t)orow * C + colbase + m] = v;
    } else {
      unsigned short o;
      if constexpr (RELU) o = f2bf_relu(v);
      else                o = f2bf(v);
      ((unsigned short*)outv)[(size_t)orow * C + colbase + m] = o;
    }
  }
}

// Fused: h1 = relu(A@WaT^T + B@WbT^T + b1), then mbuf2 = relu(h1@WcT^T + b2p).
// Block = 4 waves = one 16-row tile; h1 tile round-trips through LDS.
template<int AMODE>
__global__ __launch_bounds__(256) void mfma_mm_fused(
    const void* __restrict__ Av, const unsigned short* __restrict__ Bv,
    const unsigned short* __restrict__ WaT, const unsigned short* __restrict__ WbT,
    const float* __restrict__ bias1,
    const unsigned short* __restrict__ WcT, const float* __restrict__ bias2,
    const int* __restrict__ flags,
    unsigned short* __restrict__ out1, unsigned short* __restrict__ out2, int N)
{
  constexpr int K = 64, C = 64, LDH = 72;
  __shared__ unsigned short hl[16 * LDH];
  int wid = threadIdx.x >> 6, lane = threadIdx.x & 63;
  int rt = blockIdx.x;
  int m = lane & 15, quad = lane >> 4;
  int row = rt * 16 + m;
  int rowc = row < N ? row : N - 1;
  int colbase = wid * 16;
  int koq = quad * 8;
  bool af32 = (AMODE == 2) && (flags[0] == 0);

  f32x4 acc = {0.f, 0.f, 0.f, 0.f};
  #pragma unroll
  for (int k0 = 0; k0 < K; k0 += 32){
    short8 af = af32 ? ld_fragA_f32((const float*)Av, rowc, K, k0 + koq)
                     : ld_fragA_bf16((const unsigned short*)Av, rowc, K, k0 + koq);
    short8 wf = *(const short8*)(WaT + (size_t)(colbase + m) * K + k0 + koq);
    acc = __builtin_amdgcn_mfma_f32_16x16x32_bf16(af, wf, acc, 0, 0, 0);
    short8 bf = ld_fragA_bf16(Bv, rowc, K, k0 + koq);
    short8 wg = *(const short8*)(WbT + (size_t)(colbase + m) * K + k0 + koq);
    acc = __builtin_amdgcn_mfma_f32_16x16x32_bf16(bf, wg, acc, 0, 0, 0);
  }
  float bv = bias1[colbase + m];
  #pragma unroll
  for (int r = 0; r < 4; ++r){
    int rl = quad * 4 + r;
    int orow = rt * 16 + rl;
    unsigned short hb = f2bf_relu(acc[r] + bv);
    hl[rl * LDH + colbase + m] = hb;
    if (orow < N) out1[(size_t)orow * C + colbase + m] = hb;
  }
  __syncthreads();
  f32x4 acc2 = {0.f, 0.f, 0.f, 0.f};
  #pragma unroll
  for (int k0 = 0; k0 < K; k0 += 32){
    short8 af = *(const short8*)(hl + m * LDH + k0 + koq);
    short8 wf = *(const short8*)(WcT + (size_t)(colbase + m) * K + k0 + koq);
    acc2 = __builtin_amdgcn_mfma_f32_16x16x32_bf16(af, wf, acc2, 0, 0, 0);
  }
  float b2v = bias2[colbase + m];
  #pragma unroll
  for (int r = 0; r < 4; ++r){
    int orow = rt * 16 + quad * 4 + r;
    if (orow < N)
      out2[(size_t)orow * C + colbase + m] = f2bf_relu(acc2[r] + b2v);
  }
}

static inline char* align256(char* p){
  return (char*)(((uintptr_t)p + 255) & ~(uintptr_t)255);
}

extern "C" void kernel_launch(void* const* d_in, const int* in_sizes, int n_in,
                              void* d_out, int out_size, void* d_ws, size_t ws_size,
                              hipStream_t stream)
{
  const void* x = d_in[0];
  const void* ei = d_in[1];
  int N = in_sizes[0] / 64;   // 100000
  int E = in_sizes[1] / 2;    // 1600000

  char* ws = (char*)d_ws;
  unsigned short* wtbase = (unsigned short*)ws;     // 22528 ushorts (45KB)
  float* bbase = (float*)(ws + 65536);              // 256 floats
  int* flags = (int*)(ws + 131072 - 256);

  int S = 7, NB = (N + 127) >> 7;
  while (NB > 1024){ S++; NB = (N + (1 << S) - 1) >> S; }

  char* p = ws + 131072;
  int* row_ptr = (int*)p; p = align256(p + (size_t)(N + 1) * 4);
  uint* chist  = (uint*)p; p = align256(p + 4352);
  int* cbase   = (int*)p; p = align256(p + 4352);
  int* ccur    = (int*)p; p = align256(p + 4352);
  int* bucket  = (int*)p; p = align256(p + (size_t)E * 4);
  char* P = p;  p = align256(p + (size_t)N * 64 * 2);   // pairs(E*4)/mbuf/h2
  char* Q = p;  p = align256(p + (size_t)N * 64 * 2);   // aggb/ssum
  char* R = p;  p = align256(p + (size_t)N * 64 * 2);   // h1
  uint* pairs = (uint*)P;                               // E*4 <= N*128
  unsigned short* mbuf = (unsigned short*)P;
  unsigned short* h2   = (unsigned short*)P;   // after mbuf dead
  unsigned short* aggb = (unsigned short*)Q;
  unsigned short* ssum = (unsigned short*)Q;   // after aggb dead
  unsigned short* h1   = (unsigned short*)R;

  hipLaunchKernelGGL(detect_kernel, dim3(1), dim3(64), 0, stream,
                     (const unsigned short*)x, (const int*)ei, flags, chist);

  WConv wc;
  {
    const int widx[13] = {2, 3, 4, 5, 6, 7, 8, 9, 10, 11, 12, 13, 14};
    const int isb[13]  = {0, 1, 0, 0, 1, 0, 1, 0, 0, 1, 0, 0, 1};
    const int Cs[13]   = {6, 0, 6, 6, 0, 6, 0, 5, 5, 0, 5, 5, 0};
    const int Kk[13]   = {64, 0, 64, 64, 0, 64, 0, 64, 64, 0, 32, 32, 0};
    const int off[13]  = {0, 0, 4096, 8192, 64, 12288, 128, 16384, 18432, 192,
                          20480, 21504, 224};
    for (int i = 0; i < 13; ++i){
      wc.src[i] = d_in[widx[i]]; wc.n[i] = in_sizes[widx[i]];
      wc.isbias[i] = isb[i]; wc.Cs[i] = Cs[i]; wc.K[i] = Kk[i]; wc.off[i] = off[i];
    }
  }
  hipLaunchKernelGGL(conv_w, dim3(13), dim3(256), 0, stream, wc, wtbase, bbase, flags);
  unsigned short* W1pT = wtbase + 0;     unsigned short* W1sT = wtbase + 4096;
  unsigned short* W1nT = wtbase + 8192;  unsigned short* W2pT = wtbase + 12288;
  unsigned short* W2sT = wtbase + 16384; unsigned short* W2nT = wtbase + 18432;
  unsigned short* W3sT = wtbase + 20480; unsigned short* W3nT = wtbase + 21504;
  float* b1p = bbase + 0;  float* b1 = bbase + 64; float* b2p = bbase + 128;
  float* b2 = bbase + 192; float* b3 = bbase + 224;

  // ---- CSR build ----
  int nP = (E + CSR_CE - 1) / CSR_CE;
  csr_phase0<<<nP, 256, 0, stream>>>(ei, flags, chist, E, N, NB, S);
  csr_scan0<<<1, 256, 0, stream>>>(chist, cbase, ccur, row_ptr + N, NB);
  csr_phase1<<<nP, 256, 0, stream>>>(ei, flags, ccur, pairs, E, N, NB, S);
  csr_phase2<<<NB, 256, 0, stream>>>(cbase, pairs, bucket, row_ptr, N, S);

  int RT = (N + 15) / 16;
  int gc2 = (RT * 2 + 3) / 4;   // CT=2 kernels
  int gg = (N + 7) / 8;         // gathers: 4 waves/block x 2 nodes/wave

  // ---- layer 1 (pool 64->64, relu) + layer-2 pool transform fused ----
  mfma_mm<64,0,4,true,false,false,2><<<RT,256,0,stream>>>(
      x, nullptr, W1pT, nullptr, b1p, nullptr, flags, mbuf, N);
  gather_max64<<<gg,256,0,stream>>>(row_ptr, bucket, mbuf, aggb, N);
  mfma_mm_fused<2><<<RT,256,0,stream>>>(
      x, aggb, W1sT, W1nT, b1, W2pT, b2p, flags, h1, mbuf, N);

  // ---- layer 2 (pool 64->32) ----
  gather_max64<<<gg,256,0,stream>>>(row_ptr, bucket, mbuf, aggb, N);
  mfma_mm<64,64,2,false,false,false,0><<<gc2,256,0,stream>>>(
      h1, aggb, W2sT, W2nT, b2, nullptr, flags, h2, N);

  // ---- layer 3 (mean 32->32, f32 out) ----
  gather_sum32<<<gg,256,0,stream>>>(row_ptr, bucket, h2, ssum, N);
  mfma_mm<32,32,2,false,true,true,0><<<gc2,256,0,stream>>>(
      h2, ssum, W3sT, W3nT, b3, row_ptr, flags, d_out, N);
}

// Round 10
// 307.457 us; speedup vs baseline: 2.2245x; 1.1192x over previous
//
#include <hip/hip_runtime.h>
#include <hip/hip_bf16.h>

// GraphSAGE 3-layer: pool(64->64) -> pool(64->32) -> mean(32->32)
// R10: overhead elimination (gathers are at their locality floor: sum32 pinned
// at ~43us across 3 implementations, FETCH = 8 XCD x working set).
// (1) fixed-capacity bucket slabs kill csr_phase0 (full edge pass) + chist;
// (2) detect merged into conv_w; (3) gather_sum32 + mm3 fused (LDS A-frag
// handoff, no ssum round-trip). Gather cores unchanged from R9.

typedef unsigned int uint;
typedef short short8 __attribute__((ext_vector_type(8)));
typedef float f32x4 __attribute__((ext_vector_type(4)));
typedef float f32x2 __attribute__((ext_vector_type(2)));
typedef unsigned short u16x8 __attribute__((ext_vector_type(8)));

__device__ __forceinline__ float bf2f(unsigned short h){
  return __uint_as_float(((uint)h) << 16);
}
__device__ __forceinline__ unsigned short f2bf(float f){
  uint u = __float_as_uint(f);
  u += 0x7fffu + ((u >> 16) & 1u);   // RNE
  return (unsigned short)(u >> 16);
}
__device__ __forceinline__ float lo16(uint u){ return __uint_as_float(u << 16); }
__device__ __forceinline__ float hi16(uint u){ return __uint_as_float(u & 0xffff0000u); }

__device__ __forceinline__ uint4 pkmax4(uint4 a, uint4 b){
  u16x8 x = __builtin_bit_cast(u16x8, a);
  u16x8 y = __builtin_bit_cast(u16x8, b);
  return __builtin_bit_cast(uint4, __builtin_elementwise_max(x, y));
}
__device__ __forceinline__ uint4 shflx4(uint4 a, int off){
  uint4 r;
  r.x = (uint)__shfl_xor((int)a.x, off, 64);
  r.y = (uint)__shfl_xor((int)a.y, off, 64);
  r.z = (uint)__shfl_xor((int)a.z, off, 64);
  r.w = (uint)__shfl_xor((int)a.w, off, 64);
  return r;
}
__device__ __forceinline__ f32x2 b2lo(uint u){
  f32x2 r; r.x = lo16(u); r.y = hi16(u); return r;
}

// ---------------- weight prep + dtype detect + counter zero ----------------
struct WConv {
  const void* src[13];
  int n[13], isbias[13], Cs[13], K[13], off[13];
};

// Every block self-detects (wave 0) so no separate detect kernel / dependency.
// Block 0 publishes flags[] and zeroes ccur[].
__global__ void conv_w(WConv wc, unsigned short* wtbase, float* bbase,
                       const unsigned short* x, const int* ei,
                       int* flags, int* ccur, int NB){
  __shared__ int sflags[2];
  int t = threadIdx.x;
  if (t < 64){
    int sane = 0;
    #pragma unroll
    for (int k = 0; k < 4; ++k){
      int e = (x[(t * 4 + k) * 2] >> 7) & 0xff;  // even ushort = bf16 value iff bf16
      sane += (e >= 118 && e <= 134);
    }
    #pragma unroll
    for (int off = 32; off; off >>= 1) sane += __shfl_down(sane, off, 64);
    unsigned long long b = __ballot(ei[1 + 2 * t] != 0);  // odd words 0 iff int64
    if (t == 0){ sflags[0] = (sane >= 128); sflags[1] = (b == 0ull); }
  }
  __syncthreads();
  int isbf = sflags[0];
  if (blockIdx.x == 0){
    if (t == 0){ flags[0] = sflags[0]; flags[1] = sflags[1]; }
    for (int i = t; i < NB; i += 256) ccur[i] = 0;
  }
  int bt = blockIdx.x, n = wc.n[bt];
  if (wc.isbias[bt]){
    float* d = bbase + wc.off[bt];
    for (int i = t; i < n; i += 256)
      d[i] = isbf ? bf2f(((const unsigned short*)wc.src[bt])[i])
                  : ((const float*)wc.src[bt])[i];
  } else {
    unsigned short* d = wtbase + wc.off[bt];
    int Cs = wc.Cs[bt], K = wc.K[bt], Cm = (1 << Cs) - 1;
    for (int i = t; i < n; i += 256){
      int k = i >> Cs, c = i & Cm;
      unsigned short v = isbf ? ((const unsigned short*)wc.src[bt])[i]
                              : f2bf(((const float*)wc.src[bt])[i]);
      d[c * K + k] = v;
    }
  }
}

__device__ __forceinline__ void load_edge(const void* ei, int E, int is64, int e,
                                          int& s, int& d){
  if (is64){
    const long long* p = (const long long*)ei;
    s = (int)p[e]; d = (int)p[E + e];
  } else {
    const int* p = (const int*)ei;
    s = p[e]; d = p[E + e];
  }
}

// ---------------- CSR build (fixed-capacity slabs, no phase0) ----------------
#define CSR_CE 8192

// phase1: multisplit to fixed-capacity coarse slabs (pairs[b*CAP + i]).
// packed pair = (src<<S)|(dst&(2^S-1)). ccur[b] accumulates true counts.
__global__ __launch_bounds__(256) void csr_phase1(
    const void* __restrict__ ei, const int* __restrict__ flags,
    int* __restrict__ ccur, uint* __restrict__ pairs,
    int E, int N, int NB, int S, int CAP)
{
  __shared__ uint hist[1024];
  __shared__ uint gbase[1024];
  int is64 = flags[1];
  int t = threadIdx.x;
  uint dmask = (1u << S) - 1u;
  int e0 = blockIdx.x * CSR_CE;
  for (int i = t; i < 1024; i += 256) hist[i] = 0;
  __syncthreads();
  #pragma unroll 4
  for (int it = 0; it < CSR_CE / 256; ++it){
    int e = e0 + it * 256 + t;
    if (e >= E) break;
    int s, d; load_edge(ei, E, is64, e, s, d);
    if ((unsigned)s >= (unsigned)N || (unsigned)d >= (unsigned)N) continue;
    atomicAdd(&hist[d >> S], 1u);
  }
  __syncthreads();
  for (int b = t; b < NB; b += 256){
    uint c = hist[b];
    if (c) gbase[b] = (uint)atomicAdd(&ccur[b], (int)c);
    hist[b] = 0;
  }
  __syncthreads();
  #pragma unroll 4
  for (int it = 0; it < CSR_CE / 256; ++it){
    int e = e0 + it * 256 + t;
    if (e >= E) break;
    int s, d; load_edge(ei, E, is64, e, s, d);
    if ((unsigned)s >= (unsigned)N || (unsigned)d >= (unsigned)N) continue;
    int b = d >> S;
    uint local = atomicAdd(&hist[b], 1u);
    uint pos = gbase[b] + local;
    if (pos >= (uint)CAP) pos = (uint)CAP - 1;   // pathological-skew guard
    pairs[(size_t)b * CAP + pos] = ((uint)s << S) | ((uint)d & dmask);
  }
}

// scan of final counts -> cbase[0..NB] (+ row_ptr[N] = total).
__global__ void csr_scan0(const int* __restrict__ ccur, int* __restrict__ cbase,
                          int* __restrict__ rowptrN, int NB, int CAP)
{
  __shared__ int sm[256];
  int t = threadIdx.x;
  int g = (NB + 255) / 256;          // <= 4
  int vb = t * g, v[4], s = 0;
  for (int k = 0; k < g; ++k){
    int i = vb + k; int x = (i < NB) ? min(ccur[i], CAP) : 0; v[k] = x; s += x;
  }
  sm[t] = s; __syncthreads();
  for (int off = 1; off < 256; off <<= 1){
    int x = (t >= off) ? sm[t - off] : 0;
    __syncthreads(); sm[t] += x; __syncthreads();
  }
  int run = sm[t] - s;
  for (int k = 0; k < g; ++k){
    int i = vb + k;
    if (i < NB){ cbase[i] = run; run += v[k]; }
  }
  if (t == 255){ cbase[NB] = run; *rowptrN = run; }
}

// phase2: per-bucket hist+scan in LDS -> row_ptr slice, exact placement.
#define P2_CAP 6144
__global__ __launch_bounds__(256) void csr_phase2(
    const int* __restrict__ cbase, const int* __restrict__ ccur,
    const uint* __restrict__ pairs,
    int* __restrict__ bucket, int* __restrict__ row_ptr, int N, int S, int CAP)
{
  __shared__ int lbuf[P2_CAP];
  __shared__ int cur[1024];
  __shared__ int sm[256];
  int b = blockIdx.x, t = threadIdx.x;
  uint dmask = (1u << S) - 1u;
  int n0 = b << S;
  int n1 = n0 + (1 << S); if (n1 > N) n1 = N;
  int nn = n1 - n0;
  int base = cbase[b];
  int cnt = min(ccur[b], CAP);
  const uint* bp = pairs + (size_t)b * CAP;

  for (int i = t; i < nn; i += 256) cur[i] = 0;
  __syncthreads();
  for (int j = t; j < cnt; j += 256)
    atomicAdd(&cur[(int)(bp[j] & dmask)], 1);
  __syncthreads();
  int g = (nn + 255) / 256, vb = t * g, v[4], s = 0;
  for (int k = 0; k < g; ++k){
    int i = vb + k; int x = (i < nn) ? cur[i] : 0; v[k] = x; s += x;
  }
  sm[t] = s; __syncthreads();
  for (int off = 1; off < 256; off <<= 1){
    int x = (t >= off) ? sm[t - off] : 0;
    __syncthreads(); sm[t] += x; __syncthreads();
  }
  int run = sm[t] - s;
  for (int k = 0; k < g; ++k){
    int i = vb + k;
    if (i < nn){ row_ptr[n0 + i] = base + run; cur[i] = run; run += v[k]; }
  }
  __syncthreads();
  if (cnt <= 0) return;
  if (cnt <= P2_CAP){
    for (int j = t; j < cnt; j += 256){
      uint pr = bp[j];
      int pos = atomicAdd(&cur[(int)(pr & dmask)], 1);
      lbuf[pos] = (int)(pr >> S);
    }
    __syncthreads();
    for (int i = t; i < cnt; i += 256) bucket[base + i] = lbuf[i];
  } else {
    for (int j = t; j < cnt; j += 256){
      uint pr = bp[j];
      int pos = atomicAdd(&cur[(int)(pr & dmask)], 1);
      bucket[base + pos] = (int)(pr >> S);
    }
  }
}

// ---------------- gather-reduce: two nodes per wave (unchanged core) --------
__global__ __launch_bounds__(256) void gather_max64(
    const int* __restrict__ row_ptr, const int* __restrict__ bucket,
    const unsigned short* __restrict__ m, unsigned short* __restrict__ agg, int N)
{
  int wave = (int)((blockIdx.x * 256u + threadIdx.x) >> 6);
  int lane = threadIdx.x & 63;
  int nodeA = wave * 2, nodeB = nodeA + 1;
  if (nodeA >= N) return;
  bool hasB = nodeB < N;
  int rsA = row_ptr[nodeA], reA = row_ptr[nodeA + 1];
  int cntA = reA - rsA;
  int rsB = reA, cntB = hasB ? (row_ptr[nodeB + 1] - reA) : 0;
  int fg8 = (lane & 7) * 8, rowsel = lane >> 3;
  uint4 accA = {0u,0u,0u,0u}, accB = {0u,0u,0u,0u};
  int cmax = max(cntA, cntB);
  for (int c0 = 0; c0 < cmax; c0 += 64){
    int chA = min(cntA - c0, 64);
    int chB = min(cntB - c0, 64);
    int bvA = (lane < chA) ? bucket[rsA + c0 + lane] : 0;
    int bvB = (lane < chB) ? bucket[rsB + c0 + lane] : 0;
    int it = (max(chA, chB) + 7) >> 3;
    for (int k = 0; k < it; ++k){
      int j = k * 8 + rowsel;
      int sA = __shfl(bvA, j, 64);
      int sB = __shfl(bvB, j, 64);
      uint4 vA = *(const uint4*)(m + (size_t)sA * 64 + fg8);
      uint4 vB = *(const uint4*)(m + (size_t)sB * 64 + fg8);
      if (j < chA) accA = pkmax4(accA, vA);
      if (j < chB) accB = pkmax4(accB, vB);
    }
  }
  #pragma unroll
  for (int off = 8; off <= 32; off <<= 1){
    accA = pkmax4(accA, shflx4(accA, off));
    accB = pkmax4(accB, shflx4(accB, off));
  }
  if (lane < 8){
    *(uint4*)(agg + (size_t)nodeA * 64 + fg8) = accA;
  } else if (lane < 16 && hasB){
    *(uint4*)(agg + (size_t)nodeB * 64 + (lane & 7) * 8) = accB;
  }
}

// ---------------- MFMA dense transforms ----------------
__device__ __forceinline__ short8 ld_fragA_bf16(const unsigned short* A, int row,
                                                int K, int koff){
  return *(const short8*)(A + (size_t)row * K + koff);
}
__device__ __forceinline__ short8 ld_fragA_f32(const float* A, int row,
                                               int K, int koff){
  const float* q = A + (size_t)row * K + koff;
  float4 f0 = *(const float4*)q;
  float4 f1 = *(const float4*)(q + 4);
  short8 r;
  r[0] = (short)f2bf(f0.x); r[1] = (short)f2bf(f0.y);
  r[2] = (short)f2bf(f0.z); r[3] = (short)f2bf(f0.w);
  r[4] = (short)f2bf(f1.x); r[5] = (short)f2bf(f1.y);
  r[6] = (short)f2bf(f1.z); r[7] = (short)f2bf(f1.w);
  return r;
}
// relu bf16 with -0.0 (0x8000) squashed so packed-u16 max stays exact.
__device__ __forceinline__ unsigned short f2bf_relu(float f){
  return (unsigned short)(f2bf(fmaxf(f, 0.f)) & 0x7fff);
}

// KA in {32,64}; KB in {0,64}; CT = C/16 in {2,4}; AMODE: 0=bf16, 2=runtime.
template<int KA, int KB, int CT, bool RELU, bool OUTF32, int AMODE>
__global__ __launch_bounds__(256) void mfma_mm(
    const void* __restrict__ Av, const unsigned short* __restrict__ Bv,
    const unsigned short* __restrict__ WaT, const unsigned short* __restrict__ WbT,
    const float* __restrict__ bias,
    const int* __restrict__ flags, void* __restrict__ outv, int N)
{
  constexpr int C = CT * 16;
  int wid = threadIdx.x >> 6, lane = threadIdx.x & 63;
  int g = blockIdx.x * 4 + wid;
  int rt, ct;
  if constexpr (CT == 4){ rt = g >> 2; ct = g & 3; }
  else                  { rt = g >> 1; ct = g & 1; }
  int RT = (N + 15) >> 4;
  if (rt >= RT) return;
  int m = lane & 15, quad = lane >> 4;
  int row = rt * 16 + m;
  int rowc = row < N ? row : N - 1;
  int colbase = ct * 16;
  int koq = quad * 8;

  bool af32 = (AMODE == 2) && (flags[0] == 0);
  f32x4 accS = {0.f, 0.f, 0.f, 0.f};

  #pragma unroll
  for (int k0 = 0; k0 < KA; k0 += 32){
    short8 af = af32 ? ld_fragA_f32((const float*)Av, rowc, KA, k0 + koq)
                     : ld_fragA_bf16((const unsigned short*)Av, rowc, KA, k0 + koq);
    short8 wf = *(const short8*)(WaT + (size_t)(colbase + m) * KA + k0 + koq);
    accS = __builtin_amdgcn_mfma_f32_16x16x32_bf16(af, wf, accS, 0, 0, 0);
  }
  if constexpr (KB > 0){
    #pragma unroll
    for (int k0 = 0; k0 < KB; k0 += 32){
      short8 bf = ld_fragA_bf16(Bv, rowc, KB, k0 + koq);
      short8 wf = *(const short8*)(WbT + (size_t)(colbase + m) * KB + k0 + koq);
      accS = __builtin_amdgcn_mfma_f32_16x16x32_bf16(bf, wf, accS, 0, 0, 0);
    }
  }
  float bv = bias[colbase + m];
  #pragma unroll
  for (int r = 0; r < 4; ++r){
    int orow = rt * 16 + quad * 4 + r;
    if (orow >= N) continue;
    float v = accS[r] + bv;
    if constexpr (OUTF32){
      if constexpr (RELU) v = fmaxf(v, 0.f);
      ((float*)outv)[(size_t)orow * C + colbase + m] = v;
    } else {
      unsigned short o;
      if constexpr (RELU) o = f2bf_relu(v);
      else                o = f2bf(v);
      ((unsigned short*)outv)[(size_t)orow * C + colbase + m] = o;
    }
  }
}

// Fused: h1 = relu(A@WaT^T + B@WbT^T + b1), then mbuf2 = relu(h1@WcT^T + b2p).
template<int AMODE>
__global__ __launch_bounds__(256) void mfma_mm_fused(
    const void* __restrict__ Av, const unsigned short* __restrict__ Bv,
    const unsigned short* __restrict__ WaT, const unsigned short* __restrict__ WbT,
    const float* __restrict__ bias1,
    const unsigned short* __restrict__ WcT, const float* __restrict__ bias2,
    const int* __restrict__ flags,
    unsigned short* __restrict__ out1, unsigned short* __restrict__ out2, int N)
{
  constexpr int K = 64, C = 64, LDH = 72;
  __shared__ unsigned short hl[16 * LDH];
  int wid = threadIdx.x >> 6, lane = threadIdx.x & 63;
  int rt = blockIdx.x;
  int m = lane & 15, quad = lane >> 4;
  int row = rt * 16 + m;
  int rowc = row < N ? row : N - 1;
  int colbase = wid * 16;
  int koq = quad * 8;
  bool af32 = (AMODE == 2) && (flags[0] == 0);

  f32x4 acc = {0.f, 0.f, 0.f, 0.f};
  #pragma unroll
  for (int k0 = 0; k0 < K; k0 += 32){
    short8 af = af32 ? ld_fragA_f32((const float*)Av, rowc, K, k0 + koq)
                     : ld_fragA_bf16((const unsigned short*)Av, rowc, K, k0 + koq);
    short8 wf = *(const short8*)(WaT + (size_t)(colbase + m) * K + k0 + koq);
    acc = __builtin_amdgcn_mfma_f32_16x16x32_bf16(af, wf, acc, 0, 0, 0);
    short8 bf = ld_fragA_bf16(Bv, rowc, K, k0 + koq);
    short8 wg = *(const short8*)(WbT + (size_t)(colbase + m) * K + k0 + koq);
    acc = __builtin_amdgcn_mfma_f32_16x16x32_bf16(bf, wg, acc, 0, 0, 0);
  }
  float bv = bias1[colbase + m];
  #pragma unroll
  for (int r = 0; r < 4; ++r){
    int rl = quad * 4 + r;
    int orow = rt * 16 + rl;
    unsigned short hb = f2bf_relu(acc[r] + bv);
    hl[rl * LDH + colbase + m] = hb;
    if (orow < N) out1[(size_t)orow * C + colbase + m] = hb;
  }
  __syncthreads();
  f32x4 acc2 = {0.f, 0.f, 0.f, 0.f};
  #pragma unroll
  for (int k0 = 0; k0 < K; k0 += 32){
    short8 af = *(const short8*)(hl + m * LDH + k0 + koq);
    short8 wf = *(const short8*)(WcT + (size_t)(colbase + m) * K + k0 + koq);
    acc2 = __builtin_amdgcn_mfma_f32_16x16x32_bf16(af, wf, acc2, 0, 0, 0);
  }
  float b2v = bias2[colbase + m];
  #pragma unroll
  for (int r = 0; r < 4; ++r){
    int orow = rt * 16 + quad * 4 + r;
    if (orow < N)
      out2[(size_t)orow * C + colbase + m] = f2bf_relu(acc2[r] + b2v);
  }
}

// Fused layer 3: mean-gather (block = 16 nodes, 4 waves x 4 nodes x 16 lanes,
// 16 rows per wave-load) -> LDS agg tile -> MFMA (h2@W3s + agg@W3n + b3).
__global__ __launch_bounds__(256) void gsum3(
    const int* __restrict__ row_ptr, const int* __restrict__ bucket,
    const unsigned short* __restrict__ h2,
    const unsigned short* __restrict__ W3sT, const unsigned short* __restrict__ W3nT,
    const float* __restrict__ b3, float* __restrict__ out, int N)
{
  constexpr int LDA = 40;   // ushort stride: 80B, 16B-aligned rows
  __shared__ unsigned short la[16 * LDA];
  int t = threadIdx.x;
  int w = t >> 6, lane = t & 63;
  int n0 = blockIdx.x * 16;
  // ---- gather: group g (16 lanes) handles node n0 + w*4 + g ----
  int g = lane >> 4, q = lane & 15;
  int nd = n0 + w * 4 + g;
  int ndc = nd < N ? nd : N - 1;
  int rs = row_ptr[ndc];
  int cnt = (nd < N) ? (row_ptr[ndc + 1] - rs) : 0;
  int fg8 = (q & 3) * 8, rowsel = q >> 2;
  f32x2 a0 = {0.f,0.f}, a1 = {0.f,0.f}, a2 = {0.f,0.f}, a3 = {0.f,0.f};
  for (int c0 = 0; c0 < cnt; c0 += 16){
    int chunk = min(cnt - c0, 16);
    int bval = (q < chunk) ? bucket[rs + c0 + q] : 0;
    int it = (chunk + 3) >> 2;
    for (int k = 0; k < it; ++k){
      int j = k * 4 + rowsel;          // 0..15 group-local
      int s = __shfl(bval, (g << 4) + j, 64);
      uint4 v = *(const uint4*)(h2 + (size_t)s * 32 + fg8);
      if (j < chunk){
        a0 += b2lo(v.x); a1 += b2lo(v.y); a2 += b2lo(v.z); a3 += b2lo(v.w);
      }
    }
  }
  #pragma unroll
  for (int off = 4; off <= 8; off <<= 1){
    a0.x += __shfl_xor(a0.x, off, 64); a0.y += __shfl_xor(a0.y, off, 64);
    a1.x += __shfl_xor(a1.x, off, 64); a1.y += __shfl_xor(a1.y, off, 64);
    a2.x += __shfl_xor(a2.x, off, 64); a2.y += __shfl_xor(a2.y, off, 64);
    a3.x += __shfl_xor(a3.x, off, 64); a3.y += __shfl_xor(a3.y, off, 64);
  }
  if (rowsel == 0){                      // q < 4: lanes own features q*8..q*8+7
    float sc = 1.f / fmaxf((float)cnt, 1.f);
    int r = w * 4 + g;
    uint4 pk;
    pk.x = (uint)f2bf(a0.x * sc) | ((uint)f2bf(a0.y * sc) << 16);
    pk.y = (uint)f2bf(a1.x * sc) | ((uint)f2bf(a1.y * sc) << 16);
    pk.z = (uint)f2bf(a2.x * sc) | ((uint)f2bf(a2.y * sc) << 16);
    pk.w = (uint)f2bf(a3.x * sc) | ((uint)f2bf(a3.y * sc) << 16);
    *(uint4*)(la + r * LDA + q * 8) = pk;
  }
  __syncthreads();
  // ---- mm: waves 0,1 compute col-tiles 0,1 of the 16x32 output ----
  if (w < 2){
    int m = lane & 15, quad = lane >> 4, koq = quad * 8;
    int colbase = w * 16;
    int row = n0 + m;
    int rowc = row < N ? row : N - 1;
    f32x4 acc = {0.f, 0.f, 0.f, 0.f};
    short8 aself = *(const short8*)(h2 + (size_t)rowc * 32 + koq);
    short8 wfs = *(const short8*)(W3sT + (size_t)(colbase + m) * 32 + koq);
    acc = __builtin_amdgcn_mfma_f32_16x16x32_bf16(aself, wfs, acc, 0, 0, 0);
    short8 aagg = *(const short8*)(la + m * LDA + koq);
    short8 wfn = *(const short8*)(W3nT + (size_t)(colbase + m) * 32 + koq);
    acc = __builtin_amdgcn_mfma_f32_16x16x32_bf16(aagg, wfn, acc, 0, 0, 0);
    float bv = b3[colbase + m];
    #pragma unroll
    for (int r = 0; r < 4; ++r){
      int orow = n0 + quad * 4 + r;
      if (orow < N) out[(size_t)orow * 32 + colbase + m] = acc[r] + bv;
    }
  }
}

static inline char* align256(char* p){
  return (char*)(((uintptr_t)p + 255) & ~(uintptr_t)255);
}

extern "C" void kernel_launch(void* const* d_in, const int* in_sizes, int n_in,
                              void* d_out, int out_size, void* d_ws, size_t ws_size,
                              hipStream_t stream)
{
  const void* x = d_in[0];
  const void* ei = d_in[1];
  int N = in_sizes[0] / 64;   // 100000
  int E = in_sizes[1] / 2;    // 1600000

  char* ws = (char*)d_ws;
  unsigned short* wtbase = (unsigned short*)ws;     // 22528 ushorts (45KB)
  float* bbase = (float*)(ws + 65536);              // 256 floats
  int* flags = (int*)(ws + 131072 - 256);

  int S = 7, NB = (N + 127) >> 7;
  while (NB > 1024){ S++; NB = (N + (1 << S) - 1) >> S; }
  int CAP = ((2 * E / NB) + 255) & ~255;
  if (CAP < 1024) CAP = 1024;

  char* p = ws + 131072;
  int* row_ptr = (int*)p; p = align256(p + (size_t)(N + 1) * 4);
  int* cbase   = (int*)p; p = align256(p + 4352);
  int* ccur    = (int*)p; p = align256(p + 4352);
  int* bucket  = (int*)p; p = align256(p + (size_t)E * 4);
  uint* pairs  = (uint*)p; p = align256(p + (size_t)NB * CAP * 4);
  char* P = p;  p = align256(p + (size_t)N * 64 * 2);   // mbuf / h2
  char* Q = p;  p = align256(p + (size_t)N * 64 * 2);   // aggb
  char* R = p;  p = align256(p + (size_t)N * 64 * 2);   // h1
  unsigned short* mbuf = (unsigned short*)P;
  unsigned short* h2   = (unsigned short*)P;   // after mbuf dead
  unsigned short* aggb = (unsigned short*)Q;
  unsigned short* h1   = (unsigned short*)R;

  WConv wc;
  {
    const int widx[13] = {2, 3, 4, 5, 6, 7, 8, 9, 10, 11, 12, 13, 14};
    const int isb[13]  = {0, 1, 0, 0, 1, 0, 1, 0, 0, 1, 0, 0, 1};
    const int Cs[13]   = {6, 0, 6, 6, 0, 6, 0, 5, 5, 0, 5, 5, 0};
    const int Kk[13]   = {64, 0, 64, 64, 0, 64, 0, 64, 64, 0, 32, 32, 0};
    const int off[13]  = {0, 0, 4096, 8192, 64, 12288, 128, 16384, 18432, 192,
                          20480, 21504, 224};
    for (int i = 0; i < 13; ++i){
      wc.src[i] = d_in[widx[i]]; wc.n[i] = in_sizes[widx[i]];
      wc.isbias[i] = isb[i]; wc.Cs[i] = Cs[i]; wc.K[i] = Kk[i]; wc.off[i] = off[i];
    }
  }
  hipLaunchKernelGGL(conv_w, dim3(13), dim3(256), 0, stream, wc, wtbase, bbase,
                     (const unsigned short*)x, (const int*)ei, flags, ccur, NB);
  unsigned short* W1pT = wtbase + 0;     unsigned short* W1sT = wtbase + 4096;
  unsigned short* W1nT = wtbase + 8192;  unsigned short* W2pT = wtbase + 12288;
  unsigned short* W2sT = wtbase + 16384; unsigned short* W2nT = wtbase + 18432;
  unsigned short* W3sT = wtbase + 20480; unsigned short* W3nT = wtbase + 21504;
  float* b1p = bbase + 0;  float* b1 = bbase + 64; float* b2p = bbase + 128;
  float* b2 = bbase + 192; float* b3 = bbase + 224;

  // ---- CSR build (phase0-free: fixed-capacity slabs) ----
  int nP = (E + CSR_CE - 1) / CSR_CE;
  csr_phase1<<<nP, 256, 0, stream>>>(ei, flags, ccur, pairs, E, N, NB, S, CAP);
  csr_scan0<<<1, 256, 0, stream>>>(ccur, cbase, row_ptr + N, NB, CAP);
  csr_phase2<<<NB, 256, 0, stream>>>(cbase, ccur, pairs, bucket, row_ptr, N, S, CAP);

  int RT = (N + 15) / 16;
  int gc2 = (RT * 2 + 3) / 4;   // CT=2 kernels
  int gg = (N + 7) / 8;         // gathers: 4 waves/block x 2 nodes/wave

  // ---- layer 1 (pool 64->64, relu) + layer-2 pool transform fused ----
  mfma_mm<64,0,4,true,false,2><<<RT,256,0,stream>>>(
      x, nullptr, W1pT, nullptr, b1p, flags, mbuf, N);
  gather_max64<<<gg,256,0,stream>>>(row_ptr, bucket, mbuf, aggb, N);
  mfma_mm_fused<2><<<RT,256,0,stream>>>(
      x, aggb, W1sT, W1nT, b1, W2pT, b2p, flags, h1, mbuf, N);

  // ---- layer 2 (pool 64->32) ----
  gather_max64<<<gg,256,0,stream>>>(row_ptr, bucket, mbuf, aggb, N);
  mfma_mm<64,64,2,false,false,0><<<gc2,256,0,stream>>>(
      h1, aggb, W2sT, W2nT, b2, flags, h2, N);

  // ---- layer 3 fused (mean-gather + MFMA, f32 out) ----
  gsum3<<<RT,256,0,stream>>>(row_ptr, bucket, h2, W3sT, W3nT, b3,
                             (float*)d_out, N);
}

// Round 11
// 292.296 us; speedup vs baseline: 2.3399x; 1.0519x over previous
//
#include <hip/hip_runtime.h>
#include <hip/hip_bf16.h>

// GraphSAGE 3-layer: pool(64->64) -> pool(64->32) -> mean(32->32)
// R11: latency attack on the dense kernels (R10: mfma_mm_fused 42.7us with
// MfmaUtil 2% / VALUBusy 15% / HBM 13% -- pure load-latency bound).
// (1) 2 row-tiles per wave in mm1/fused/mm2 (2x loads in flight, half the
// weight re-reads); (2) hybrid phase1||mm1 kernel (independent work overlapped
// on one grid); (3) single-pass phase1 (edges held in registers, kills the
// second 25.6MB int64 edge read). Gather cores + gsum3 + CSR phase2 unchanged.

typedef unsigned int uint;
typedef short short8 __attribute__((ext_vector_type(8)));
typedef float f32x4 __attribute__((ext_vector_type(4)));
typedef float f32x2 __attribute__((ext_vector_type(2)));
typedef unsigned short u16x8 __attribute__((ext_vector_type(8)));

__device__ __forceinline__ float bf2f(unsigned short h){
  return __uint_as_float(((uint)h) << 16);
}
__device__ __forceinline__ unsigned short f2bf(float f){
  uint u = __float_as_uint(f);
  u += 0x7fffu + ((u >> 16) & 1u);   // RNE
  return (unsigned short)(u >> 16);
}
__device__ __forceinline__ float lo16(uint u){ return __uint_as_float(u << 16); }
__device__ __forceinline__ float hi16(uint u){ return __uint_as_float(u & 0xffff0000u); }

__device__ __forceinline__ uint4 pkmax4(uint4 a, uint4 b){
  u16x8 x = __builtin_bit_cast(u16x8, a);
  u16x8 y = __builtin_bit_cast(u16x8, b);
  return __builtin_bit_cast(uint4, __builtin_elementwise_max(x, y));
}
__device__ __forceinline__ uint4 shflx4(uint4 a, int off){
  uint4 r;
  r.x = (uint)__shfl_xor((int)a.x, off, 64);
  r.y = (uint)__shfl_xor((int)a.y, off, 64);
  r.z = (uint)__shfl_xor((int)a.z, off, 64);
  r.w = (uint)__shfl_xor((int)a.w, off, 64);
  return r;
}
__device__ __forceinline__ f32x2 b2lo(uint u){
  f32x2 r; r.x = lo16(u); r.y = hi16(u); return r;
}

// ---------------- weight prep + dtype detect + counter zero ----------------
struct WConv {
  const void* src[13];
  int n[13], isbias[13], Cs[13], K[13], off[13];
};

__global__ void conv_w(WConv wc, unsigned short* wtbase, float* bbase,
                       const unsigned short* x, const int* ei,
                       int* flags, int* ccur, int NB){
  __shared__ int sflags[2];
  int t = threadIdx.x;
  if (t < 64){
    int sane = 0;
    #pragma unroll
    for (int k = 0; k < 4; ++k){
      int e = (x[(t * 4 + k) * 2] >> 7) & 0xff;
      sane += (e >= 118 && e <= 134);
    }
    #pragma unroll
    for (int off = 32; off; off >>= 1) sane += __shfl_down(sane, off, 64);
    unsigned long long b = __ballot(ei[1 + 2 * t] != 0);
    if (t == 0){ sflags[0] = (sane >= 128); sflags[1] = (b == 0ull); }
  }
  __syncthreads();
  int isbf = sflags[0];
  if (blockIdx.x == 0){
    if (t == 0){ flags[0] = sflags[0]; flags[1] = sflags[1]; }
    for (int i = t; i < NB; i += 256) ccur[i] = 0;
  }
  int bt = blockIdx.x, n = wc.n[bt];
  if (wc.isbias[bt]){
    float* d = bbase + wc.off[bt];
    for (int i = t; i < n; i += 256)
      d[i] = isbf ? bf2f(((const unsigned short*)wc.src[bt])[i])
                  : ((const float*)wc.src[bt])[i];
  } else {
    unsigned short* d = wtbase + wc.off[bt];
    int Cs = wc.Cs[bt], K = wc.K[bt], Cm = (1 << Cs) - 1;
    for (int i = t; i < n; i += 256){
      int k = i >> Cs, c = i & Cm;
      unsigned short v = isbf ? ((const unsigned short*)wc.src[bt])[i]
                              : f2bf(((const float*)wc.src[bt])[i]);
      d[c * K + k] = v;
    }
  }
}

__device__ __forceinline__ void load_edge(const void* ei, int E, int is64, int e,
                                          int& s, int& d){
  if (is64){
    const long long* p = (const long long*)ei;
    s = (int)p[e]; d = (int)p[E + e];
  } else {
    const int* p = (const int*)ei;
    s = p[e]; d = p[E + e];
  }
}

// ---------------- MFMA helpers ----------------
__device__ __forceinline__ short8 ld_fragA_bf16(const unsigned short* A, int row,
                                                int K, int koff){
  return *(const short8*)(A + (size_t)row * K + koff);
}
__device__ __forceinline__ short8 ld_fragA_f32(const float* A, int row,
                                               int K, int koff){
  const float* q = A + (size_t)row * K + koff;
  float4 f0 = *(const float4*)q;
  float4 f1 = *(const float4*)(q + 4);
  short8 r;
  r[0] = (short)f2bf(f0.x); r[1] = (short)f2bf(f0.y);
  r[2] = (short)f2bf(f0.z); r[3] = (short)f2bf(f0.w);
  r[4] = (short)f2bf(f1.x); r[5] = (short)f2bf(f1.y);
  r[6] = (short)f2bf(f1.z); r[7] = (short)f2bf(f1.w);
  return r;
}
// relu bf16 with -0.0 (0x8000) squashed so packed-u16 max stays exact.
__device__ __forceinline__ unsigned short f2bf_relu(float f){
  return (unsigned short)(f2bf(fmaxf(f, 0.f)) & 0x7fff);
}

// ---------------- hybrid: CSR phase1 (blocks < nP) || mm1 (rest) ------------
#define CSR_CE 2048

// single-pass multisplit: 8 edges/thread held in registers.
__device__ __forceinline__ void phase1_body(
    const void* __restrict__ ei, const int* __restrict__ flags,
    int* __restrict__ ccur, uint* __restrict__ pairs,
    int E, int N, int NB, int S, int CAP, int blk,
    uint* hist, uint* gbase)
{
  int t = threadIdx.x;
  uint dmask = (1u << S) - 1u;
  int is64 = flags[1];
  int e0 = blk * CSR_CE;
  for (int i = t; i < 1024; i += 256) hist[i] = 0;
  __syncthreads();
  uint pr[8]; short bb[8];
  #pragma unroll
  for (int k = 0; k < 8; ++k){
    int e = e0 + k * 256 + t;
    int s = 0, d = 0; bool ok = (e < E);
    if (ok){
      load_edge(ei, E, is64, e, s, d);
      ok = (unsigned)s < (unsigned)N && (unsigned)d < (unsigned)N;
    }
    bb[k] = ok ? (short)(d >> S) : (short)(-1);
    pr[k] = ((uint)s << S) | ((uint)d & dmask);
    if (ok) atomicAdd(&hist[d >> S], 1u);
  }
  __syncthreads();
  for (int b = t; b < NB; b += 256){
    uint c = hist[b];
    if (c) gbase[b] = (uint)atomicAdd(&ccur[b], (int)c);
    hist[b] = 0;
  }
  __syncthreads();
  #pragma unroll
  for (int k = 0; k < 8; ++k){
    int b = (int)bb[k];
    if (b >= 0){
      uint local = atomicAdd(&hist[b], 1u);
      uint pos = gbase[b] + local;
      if (pos >= (uint)CAP) pos = (uint)CAP - 1;   // pathological-skew guard
      pairs[(size_t)b * CAP + pos] = pr[k];
    }
  }
}

// mm1: mbuf = relu(x@W1p + b1p). 2 row-tiles per wave (32 rows/block, C=64).
template<int AMODE>
__device__ __forceinline__ void mm1_body(
    const void* __restrict__ Av, const unsigned short* __restrict__ WaT,
    const float* __restrict__ bias, const int* __restrict__ flags,
    unsigned short* __restrict__ out, int N, int blk)
{
  int wid = threadIdx.x >> 6, lane = threadIdx.x & 63;
  int n0 = blk * 32;
  int m = lane & 15, quad = lane >> 4, koq = quad * 8;
  int colbase = wid * 16;
  int rowc0 = min(n0 + m, N - 1);
  int rowc1 = min(n0 + 16 + m, N - 1);
  bool af32 = (AMODE == 2) && (flags[0] == 0);
  f32x4 a0 = {0.f,0.f,0.f,0.f}, a1 = {0.f,0.f,0.f,0.f};
  #pragma unroll
  for (int k0 = 0; k0 < 64; k0 += 32){
    short8 af0 = af32 ? ld_fragA_f32((const float*)Av, rowc0, 64, k0 + koq)
                      : ld_fragA_bf16((const unsigned short*)Av, rowc0, 64, k0 + koq);
    short8 af1 = af32 ? ld_fragA_f32((const float*)Av, rowc1, 64, k0 + koq)
                      : ld_fragA_bf16((const unsigned short*)Av, rowc1, 64, k0 + koq);
    short8 wf = *(const short8*)(WaT + (size_t)(colbase + m) * 64 + k0 + koq);
    a0 = __builtin_amdgcn_mfma_f32_16x16x32_bf16(af0, wf, a0, 0, 0, 0);
    a1 = __builtin_amdgcn_mfma_f32_16x16x32_bf16(af1, wf, a1, 0, 0, 0);
  }
  float bv = bias[colbase + m];
  #pragma unroll
  for (int r = 0; r < 4; ++r){
    int rl = quad * 4 + r;
    if (n0 + rl < N)
      out[(size_t)(n0 + rl) * 64 + colbase + m] = f2bf_relu(a0[r] + bv);
    if (n0 + 16 + rl < N)
      out[(size_t)(n0 + 16 + rl) * 64 + colbase + m] = f2bf_relu(a1[r] + bv);
  }
}

template<int AMODE>
__global__ __launch_bounds__(256) void phase1_mm1(
    const void* __restrict__ ei, const int* __restrict__ flags,
    int* __restrict__ ccur, uint* __restrict__ pairs,
    int E, int N, int NB, int S, int CAP, int nP,
    const void* __restrict__ x, const unsigned short* __restrict__ W1pT,
    const float* __restrict__ b1p, unsigned short* __restrict__ mbuf)
{
  __shared__ uint hist[1024];
  __shared__ uint gbase[1024];
  if ((int)blockIdx.x < nP)
    phase1_body(ei, flags, ccur, pairs, E, N, NB, S, CAP, blockIdx.x, hist, gbase);
  else
    mm1_body<AMODE>(x, W1pT, b1p, flags, mbuf, N, blockIdx.x - nP);
}

// scan of final counts -> cbase[0..NB] (+ row_ptr[N] = total).
__global__ void csr_scan0(const int* __restrict__ ccur, int* __restrict__ cbase,
                          int* __restrict__ rowptrN, int NB, int CAP)
{
  __shared__ int sm[256];
  int t = threadIdx.x;
  int g = (NB + 255) / 256;          // <= 4
  int vb = t * g, v[4], s = 0;
  for (int k = 0; k < g; ++k){
    int i = vb + k; int x = (i < NB) ? min(ccur[i], CAP) : 0; v[k] = x; s += x;
  }
  sm[t] = s; __syncthreads();
  for (int off = 1; off < 256; off <<= 1){
    int x = (t >= off) ? sm[t - off] : 0;
    __syncthreads(); sm[t] += x; __syncthreads();
  }
  int run = sm[t] - s;
  for (int k = 0; k < g; ++k){
    int i = vb + k;
    if (i < NB){ cbase[i] = run; run += v[k]; }
  }
  if (t == 255){ cbase[NB] = run; *rowptrN = run; }
}

// phase2: per-bucket hist+scan in LDS -> row_ptr slice, exact placement.
#define P2_CAP 6144
__global__ __launch_bounds__(256) void csr_phase2(
    const int* __restrict__ cbase, const int* __restrict__ ccur,
    const uint* __restrict__ pairs,
    int* __restrict__ bucket, int* __restrict__ row_ptr, int N, int S, int CAP)
{
  __shared__ int lbuf[P2_CAP];
  __shared__ int cur[1024];
  __shared__ int sm[256];
  int b = blockIdx.x, t = threadIdx.x;
  uint dmask = (1u << S) - 1u;
  int n0 = b << S;
  int n1 = n0 + (1 << S); if (n1 > N) n1 = N;
  int nn = n1 - n0;
  int base = cbase[b];
  int cnt = min(ccur[b], CAP);
  const uint* bp = pairs + (size_t)b * CAP;

  for (int i = t; i < nn; i += 256) cur[i] = 0;
  __syncthreads();
  for (int j = t; j < cnt; j += 256)
    atomicAdd(&cur[(int)(bp[j] & dmask)], 1);
  __syncthreads();
  int g = (nn + 255) / 256, vb = t * g, v[4], s = 0;
  for (int k = 0; k < g; ++k){
    int i = vb + k; int x = (i < nn) ? cur[i] : 0; v[k] = x; s += x;
  }
  sm[t] = s; __syncthreads();
  for (int off = 1; off < 256; off <<= 1){
    int x = (t >= off) ? sm[t - off] : 0;
    __syncthreads(); sm[t] += x; __syncthreads();
  }
  int run = sm[t] - s;
  for (int k = 0; k < g; ++k){
    int i = vb + k;
    if (i < nn){ row_ptr[n0 + i] = base + run; cur[i] = run; run += v[k]; }
  }
  __syncthreads();
  if (cnt <= 0) return;
  if (cnt <= P2_CAP){
    for (int j = t; j < cnt; j += 256){
      uint pr = bp[j];
      int pos = atomicAdd(&cur[(int)(pr & dmask)], 1);
      lbuf[pos] = (int)(pr >> S);
    }
    __syncthreads();
    for (int i = t; i < cnt; i += 256) bucket[base + i] = lbuf[i];
  } else {
    for (int j = t; j < cnt; j += 256){
      uint pr = bp[j];
      int pos = atomicAdd(&cur[(int)(pr & dmask)], 1);
      bucket[base + pos] = (int)(pr >> S);
    }
  }
}

// ---------------- gather-reduce: two nodes per wave (unchanged core) --------
__global__ __launch_bounds__(256) void gather_max64(
    const int* __restrict__ row_ptr, const int* __restrict__ bucket,
    const unsigned short* __restrict__ m, unsigned short* __restrict__ agg, int N)
{
  int wave = (int)((blockIdx.x * 256u + threadIdx.x) >> 6);
  int lane = threadIdx.x & 63;
  int nodeA = wave * 2, nodeB = nodeA + 1;
  if (nodeA >= N) return;
  bool hasB = nodeB < N;
  int rsA = row_ptr[nodeA], reA = row_ptr[nodeA + 1];
  int cntA = reA - rsA;
  int rsB = reA, cntB = hasB ? (row_ptr[nodeB + 1] - reA) : 0;
  int fg8 = (lane & 7) * 8, rowsel = lane >> 3;
  uint4 accA = {0u,0u,0u,0u}, accB = {0u,0u,0u,0u};
  int cmax = max(cntA, cntB);
  for (int c0 = 0; c0 < cmax; c0 += 64){
    int chA = min(cntA - c0, 64);
    int chB = min(cntB - c0, 64);
    int bvA = (lane < chA) ? bucket[rsA + c0 + lane] : 0;
    int bvB = (lane < chB) ? bucket[rsB + c0 + lane] : 0;
    int it = (max(chA, chB) + 7) >> 3;
    for (int k = 0; k < it; ++k){
      int j = k * 8 + rowsel;
      int sA = __shfl(bvA, j, 64);
      int sB = __shfl(bvB, j, 64);
      uint4 vA = *(const uint4*)(m + (size_t)sA * 64 + fg8);
      uint4 vB = *(const uint4*)(m + (size_t)sB * 64 + fg8);
      if (j < chA) accA = pkmax4(accA, vA);
      if (j < chB) accB = pkmax4(accB, vB);
    }
  }
  #pragma unroll
  for (int off = 8; off <= 32; off <<= 1){
    accA = pkmax4(accA, shflx4(accA, off));
    accB = pkmax4(accB, shflx4(accB, off));
  }
  if (lane < 8){
    *(uint4*)(agg + (size_t)nodeA * 64 + fg8) = accA;
  } else if (lane < 16 && hasB){
    *(uint4*)(agg + (size_t)nodeB * 64 + (lane & 7) * 8) = accB;
  }
}

// Fused: h1 = relu(x@W1s + agg@W1n + b1), then mbuf2 = relu(h1@W2p + b2p).
// 2 row-tiles per wave (32 rows/block); h1 tile round-trips through LDS.
template<int AMODE>
__global__ __launch_bounds__(256) void mfma_mm_fused(
    const void* __restrict__ Av, const unsigned short* __restrict__ Bv,
    const unsigned short* __restrict__ WaT, const unsigned short* __restrict__ WbT,
    const float* __restrict__ bias1,
    const unsigned short* __restrict__ WcT, const float* __restrict__ bias2,
    const int* __restrict__ flags,
    unsigned short* __restrict__ out1, unsigned short* __restrict__ out2, int N)
{
  constexpr int K = 64, C = 64, LDH = 72;
  __shared__ unsigned short hl[32 * LDH];
  int wid = threadIdx.x >> 6, lane = threadIdx.x & 63;
  int n0 = blockIdx.x * 32;
  int m = lane & 15, quad = lane >> 4, koq = quad * 8;
  int colbase = wid * 16;
  int rowc0 = min(n0 + m, N - 1);
  int rowc1 = min(n0 + 16 + m, N - 1);
  bool af32 = (AMODE == 2) && (flags[0] == 0);

  f32x4 a0 = {0.f,0.f,0.f,0.f}, a1 = {0.f,0.f,0.f,0.f};
  #pragma unroll
  for (int k0 = 0; k0 < K; k0 += 32){
    short8 af0 = af32 ? ld_fragA_f32((const float*)Av, rowc0, K, k0 + koq)
                      : ld_fragA_bf16((const unsigned short*)Av, rowc0, K, k0 + koq);
    short8 af1 = af32 ? ld_fragA_f32((const float*)Av, rowc1, K, k0 + koq)
                      : ld_fragA_bf16((const unsigned short*)Av, rowc1, K, k0 + koq);
    short8 wf = *(const short8*)(WaT + (size_t)(colbase + m) * K + k0 + koq);
    a0 = __builtin_amdgcn_mfma_f32_16x16x32_bf16(af0, wf, a0, 0, 0, 0);
    a1 = __builtin_amdgcn_mfma_f32_16x16x32_bf16(af1, wf, a1, 0, 0, 0);
    short8 bf0 = ld_fragA_bf16(Bv, rowc0, K, k0 + koq);
    short8 bf1 = ld_fragA_bf16(Bv, rowc1, K, k0 + koq);
    short8 wg = *(const short8*)(WbT + (size_t)(colbase + m) * K + k0 + koq);
    a0 = __builtin_amdgcn_mfma_f32_16x16x32_bf16(bf0, wg, a0, 0, 0, 0);
    a1 = __builtin_amdgcn_mfma_f32_16x16x32_bf16(bf1, wg, a1, 0, 0, 0);
  }
  float bv = bias1[colbase + m];
  #pragma unroll
  for (int r = 0; r < 4; ++r){
    int rl = quad * 4 + r;
    unsigned short h0 = f2bf_relu(a0[r] + bv);
    unsigned short h1v = f2bf_relu(a1[r] + bv);
    hl[rl * LDH + colbase + m] = h0;
    hl[(16 + rl) * LDH + colbase + m] = h1v;
    if (n0 + rl < N) out1[(size_t)(n0 + rl) * C + colbase + m] = h0;
    if (n0 + 16 + rl < N) out1[(size_t)(n0 + 16 + rl) * C + colbase + m] = h1v;
  }
  __syncthreads();
  f32x4 c0 = {0.f,0.f,0.f,0.f}, c1 = {0.f,0.f,0.f,0.f};
  #pragma unroll
  for (int k0 = 0; k0 < K; k0 += 32){
    short8 q0 = *(const short8*)(hl + m * LDH + k0 + koq);
    short8 q1 = *(const short8*)(hl + (16 + m) * LDH + k0 + koq);
    short8 wf = *(const short8*)(WcT + (size_t)(colbase + m) * K + k0 + koq);
    c0 = __builtin_amdgcn_mfma_f32_16x16x32_bf16(q0, wf, c0, 0, 0, 0);
    c1 = __builtin_amdgcn_mfma_f32_16x16x32_bf16(q1, wf, c1, 0, 0, 0);
  }
  float b2v = bias2[colbase + m];
  #pragma unroll
  for (int r = 0; r < 4; ++r){
    int rl = quad * 4 + r;
    if (n0 + rl < N)
      out2[(size_t)(n0 + rl) * C + colbase + m] = f2bf_relu(c0[r] + b2v);
    if (n0 + 16 + rl < N)
      out2[(size_t)(n0 + 16 + rl) * C + colbase + m] = f2bf_relu(c1[r] + b2v);
  }
}

// mm2: h2 = h1@W2s + agg@W2n + b2 (C=32). 2 row-tiles/wave, 64 rows/block.
__global__ __launch_bounds__(256) void mfma_mm2(
    const unsigned short* __restrict__ h1, const unsigned short* __restrict__ aggb,
    const unsigned short* __restrict__ WsT, const unsigned short* __restrict__ WnT,
    const float* __restrict__ bias, unsigned short* __restrict__ h2, int N)
{
  int wid = threadIdx.x >> 6, lane = threadIdx.x & 63;
  int n0 = blockIdx.x * 64 + (wid >> 1) * 32;
  int colbase = (wid & 1) * 16;
  int m = lane & 15, quad = lane >> 4, koq = quad * 8;
  int rowc0 = min(n0 + m, N - 1), rowc1 = min(n0 + 16 + m, N - 1);
  f32x4 a0 = {0.f,0.f,0.f,0.f}, a1 = {0.f,0.f,0.f,0.f};
  #pragma unroll
  for (int k0 = 0; k0 < 64; k0 += 32){
    short8 af0 = *(const short8*)(h1 + (size_t)rowc0 * 64 + k0 + koq);
    short8 af1 = *(const short8*)(h1 + (size_t)rowc1 * 64 + k0 + koq);
    short8 wf = *(const short8*)(WsT + (size_t)(colbase + m) * 64 + k0 + koq);
    a0 = __builtin_amdgcn_mfma_f32_16x16x32_bf16(af0, wf, a0, 0, 0, 0);
    a1 = __builtin_amdgcn_mfma_f32_16x16x32_bf16(af1, wf, a1, 0, 0, 0);
    short8 bf0 = *(const short8*)(aggb + (size_t)rowc0 * 64 + k0 + koq);
    short8 bf1 = *(const short8*)(aggb + (size_t)rowc1 * 64 + k0 + koq);
    short8 wg = *(const short8*)(WnT + (size_t)(colbase + m) * 64 + k0 + koq);
    a0 = __builtin_amdgcn_mfma_f32_16x16x32_bf16(bf0, wg, a0, 0, 0, 0);
    a1 = __builtin_amdgcn_mfma_f32_16x16x32_bf16(bf1, wg, a1, 0, 0, 0);
  }
  float bv = bias[colbase + m];
  #pragma unroll
  for (int r = 0; r < 4; ++r){
    int rl = quad * 4 + r;
    if (n0 + rl < N)
      h2[(size_t)(n0 + rl) * 32 + colbase + m] = f2bf(a0[r] + bv);
    if (n0 + 16 + rl < N)
      h2[(size_t)(n0 + 16 + rl) * 32 + colbase + m] = f2bf(a1[r] + bv);
  }
}

// Fused layer 3: mean-gather (block = 16 nodes) -> LDS agg tile -> MFMA.
__global__ __launch_bounds__(256) void gsum3(
    const int* __restrict__ row_ptr, const int* __restrict__ bucket,
    const unsigned short* __restrict__ h2,
    const unsigned short* __restrict__ W3sT, const unsigned short* __restrict__ W3nT,
    const float* __restrict__ b3, float* __restrict__ out, int N)
{
  constexpr int LDA = 40;
  __shared__ unsigned short la[16 * LDA];
  int t = threadIdx.x;
  int w = t >> 6, lane = t & 63;
  int n0 = blockIdx.x * 16;
  int g = lane >> 4, q = lane & 15;
  int nd = n0 + w * 4 + g;
  int ndc = nd < N ? nd : N - 1;
  int rs = row_ptr[ndc];
  int cnt = (nd < N) ? (row_ptr[ndc + 1] - rs) : 0;
  int fg8 = (q & 3) * 8, rowsel = q >> 2;
  f32x2 a0 = {0.f,0.f}, a1 = {0.f,0.f}, a2 = {0.f,0.f}, a3 = {0.f,0.f};
  for (int c0 = 0; c0 < cnt; c0 += 16){
    int chunk = min(cnt - c0, 16);
    int bval = (q < chunk) ? bucket[rs + c0 + q] : 0;
    int it = (chunk + 3) >> 2;
    for (int k = 0; k < it; ++k){
      int j = k * 4 + rowsel;
      int s = __shfl(bval, (g << 4) + j, 64);
      uint4 v = *(const uint4*)(h2 + (size_t)s * 32 + fg8);
      if (j < chunk){
        a0 += b2lo(v.x); a1 += b2lo(v.y); a2 += b2lo(v.z); a3 += b2lo(v.w);
      }
    }
  }
  #pragma unroll
  for (int off = 4; off <= 8; off <<= 1){
    a0.x += __shfl_xor(a0.x, off, 64); a0.y += __shfl_xor(a0.y, off, 64);
    a1.x += __shfl_xor(a1.x, off, 64); a1.y += __shfl_xor(a1.y, off, 64);
    a2.x += __shfl_xor(a2.x, off, 64); a2.y += __shfl_xor(a2.y, off, 64);
    a3.x += __shfl_xor(a3.x, off, 64); a3.y += __shfl_xor(a3.y, off, 64);
  }
  if (rowsel == 0){
    float sc = 1.f / fmaxf((float)cnt, 1.f);
    int r = w * 4 + g;
    uint4 pk;
    pk.x = (uint)f2bf(a0.x * sc) | ((uint)f2bf(a0.y * sc) << 16);
    pk.y = (uint)f2bf(a1.x * sc) | ((uint)f2bf(a1.y * sc) << 16);
    pk.z = (uint)f2bf(a2.x * sc) | ((uint)f2bf(a2.y * sc) << 16);
    pk.w = (uint)f2bf(a3.x * sc) | ((uint)f2bf(a3.y * sc) << 16);
    *(uint4*)(la + r * LDA + q * 8) = pk;
  }
  __syncthreads();
  if (w < 2){
    int m = lane & 15, quad = lane >> 4, koq = quad * 8;
    int colbase = w * 16;
    int row = n0 + m;
    int rowc = row < N ? row : N - 1;
    f32x4 acc = {0.f, 0.f, 0.f, 0.f};
    short8 aself = *(const short8*)(h2 + (size_t)rowc * 32 + koq);
    short8 wfs = *(const short8*)(W3sT + (size_t)(colbase + m) * 32 + koq);
    acc = __builtin_amdgcn_mfma_f32_16x16x32_bf16(aself, wfs, acc, 0, 0, 0);
    short8 aagg = *(const short8*)(la + m * LDA + koq);
    short8 wfn = *(const short8*)(W3nT + (size_t)(colbase + m) * 32 + koq);
    acc = __builtin_amdgcn_mfma_f32_16x16x32_bf16(aagg, wfn, acc, 0, 0, 0);
    float bv = b3[colbase + m];
    #pragma unroll
    for (int r = 0; r < 4; ++r){
      int orow = n0 + quad * 4 + r;
      if (orow < N) out[(size_t)orow * 32 + colbase + m] = acc[r] + bv;
    }
  }
}

static inline char* align256(char* p){
  return (char*)(((uintptr_t)p + 255) & ~(uintptr_t)255);
}

extern "C" void kernel_launch(void* const* d_in, const int* in_sizes, int n_in,
                              void* d_out, int out_size, void* d_ws, size_t ws_size,
                              hipStream_t stream)
{
  const void* x = d_in[0];
  const void* ei = d_in[1];
  int N = in_sizes[0] / 64;   // 100000
  int E = in_sizes[1] / 2;    // 1600000

  char* ws = (char*)d_ws;
  unsigned short* wtbase = (unsigned short*)ws;     // 22528 ushorts (45KB)
  float* bbase = (float*)(ws + 65536);              // 256 floats
  int* flags = (int*)(ws + 131072 - 256);

  int S = 7, NB = (N + 127) >> 7;
  while (NB > 1024){ S++; NB = (N + (1 << S) - 1) >> S; }
  int CAP = ((2 * E / NB) + 255) & ~255;
  if (CAP < 1024) CAP = 1024;

  char* p = ws + 131072;
  int* row_ptr = (int*)p; p = align256(p + (size_t)(N + 1) * 4);
  int* cbase   = (int*)p; p = align256(p + 4352);
  int* ccur    = (int*)p; p = align256(p + 4352);
  int* bucket  = (int*)p; p = align256(p + (size_t)E * 4);
  uint* pairs  = (uint*)p; p = align256(p + (size_t)NB * CAP * 4);
  char* P = p;  p = align256(p + (size_t)N * 64 * 2);   // mbuf / h2
  char* Q = p;  p = align256(p + (size_t)N * 64 * 2);   // aggb
  char* R = p;  p = align256(p + (size_t)N * 64 * 2);   // h1
  unsigned short* mbuf = (unsigned short*)P;
  unsigned short* h2   = (unsigned short*)P;   // after mbuf dead
  unsigned short* aggb = (unsigned short*)Q;
  unsigned short* h1   = (unsigned short*)R;

  WConv wc;
  {
    const int widx[13] = {2, 3, 4, 5, 6, 7, 8, 9, 10, 11, 12, 13, 14};
    const int isb[13]  = {0, 1, 0, 0, 1, 0, 1, 0, 0, 1, 0, 0, 1};
    const int Cs[13]   = {6, 0, 6, 6, 0, 6, 0, 5, 5, 0, 5, 5, 0};
    const int Kk[13]   = {64, 0, 64, 64, 0, 64, 0, 64, 64, 0, 32, 32, 0};
    const int off[13]  = {0, 0, 4096, 8192, 64, 12288, 128, 16384, 18432, 192,
                          20480, 21504, 224};
    for (int i = 0; i < 13; ++i){
      wc.src[i] = d_in[widx[i]]; wc.n[i] = in_sizes[widx[i]];
      wc.isbias[i] = isb[i]; wc.Cs[i] = Cs[i]; wc.K[i] = Kk[i]; wc.off[i] = off[i];
    }
  }
  hipLaunchKernelGGL(conv_w, dim3(13), dim3(256), 0, stream, wc, wtbase, bbase,
                     (const unsigned short*)x, (const int*)ei, flags, ccur, NB);
  unsigned short* W1pT = wtbase + 0;     unsigned short* W1sT = wtbase + 4096;
  unsigned short* W1nT = wtbase + 8192;  unsigned short* W2pT = wtbase + 12288;
  unsigned short* W2sT = wtbase + 16384; unsigned short* W2nT = wtbase + 18432;
  unsigned short* W3sT = wtbase + 20480; unsigned short* W3nT = wtbase + 21504;
  float* b1p = bbase + 0;  float* b1 = bbase + 64; float* b2p = bbase + 128;
  float* b2 = bbase + 192; float* b3 = bbase + 224;

  int nP = (E + CSR_CE - 1) / CSR_CE;
  int RT32 = (N + 31) / 32;
  int RT16 = (N + 15) / 16;
  int gg = (N + 7) / 8;         // gathers: 4 waves/block x 2 nodes/wave

  // ---- hybrid: CSR phase1 || mm1 (independent work, one grid) ----
  phase1_mm1<2><<<nP + RT32, 256, 0, stream>>>(
      ei, flags, ccur, pairs, E, N, NB, S, CAP, nP, x, W1pT, b1p, mbuf);
  csr_scan0<<<1, 256, 0, stream>>>(ccur, cbase, row_ptr + N, NB, CAP);
  csr_phase2<<<NB, 256, 0, stream>>>(cbase, ccur, pairs, bucket, row_ptr, N, S, CAP);

  // ---- layer 1 (pool 64->64, relu) + layer-2 pool transform fused ----
  gather_max64<<<gg,256,0,stream>>>(row_ptr, bucket, mbuf, aggb, N);
  mfma_mm_fused<2><<<RT32,256,0,stream>>>(
      x, aggb, W1sT, W1nT, b1, W2pT, b2p, flags, h1, mbuf, N);

  // ---- layer 2 (pool 64->32) ----
  gather_max64<<<gg,256,0,stream>>>(row_ptr, bucket, mbuf, aggb, N);
  mfma_mm2<<<(N + 63) / 64,256,0,stream>>>(h1, aggb, W2sT, W2nT, b2, h2, N);

  // ---- layer 3 fused (mean-gather + MFMA, f32 out) ----
  gsum3<<<RT16,256,0,stream>>>(row_ptr, bucket, h2, W3sT, W3nT, b3,
                               (float*)d_out, N);
}

// Round 12
// 274.022 us; speedup vs baseline: 2.4960x; 1.0667x over previous
//
#include <hip/hip_runtime.h>
#include <hip/hip_bf16.h>

// GraphSAGE 3-layer: pool(64->64) -> pool(64->32) -> mean(32->32)
// R12: (1) phase1 back to two-pass CSR_CE=8192 (R11's CE=2048 single-pass
// 4x'd block count -> ~600K contended global ccur atomics; slab stays in
// XCD L2 between passes so pass 2 is ~free); (2) max-gathers fused into
// their consumer MMs via LDS A-frag tiles (kills 2 launches + 2x12.8MB aggb
// round-trips; gather latency of block i overlaps MFMA of block j).
// m2 now goes to a separate buffer (old aggb region) -- blocks still read m1.

typedef unsigned int uint;
typedef short short8 __attribute__((ext_vector_type(8)));
typedef float f32x4 __attribute__((ext_vector_type(4)));
typedef float f32x2 __attribute__((ext_vector_type(2)));
typedef unsigned short u16x8 __attribute__((ext_vector_type(8)));

__device__ __forceinline__ float bf2f(unsigned short h){
  return __uint_as_float(((uint)h) << 16);
}
__device__ __forceinline__ unsigned short f2bf(float f){
  uint u = __float_as_uint(f);
  u += 0x7fffu + ((u >> 16) & 1u);   // RNE
  return (unsigned short)(u >> 16);
}
__device__ __forceinline__ float lo16(uint u){ return __uint_as_float(u << 16); }
__device__ __forceinline__ float hi16(uint u){ return __uint_as_float(u & 0xffff0000u); }

__device__ __forceinline__ uint4 pkmax4(uint4 a, uint4 b){
  u16x8 x = __builtin_bit_cast(u16x8, a);
  u16x8 y = __builtin_bit_cast(u16x8, b);
  return __builtin_bit_cast(uint4, __builtin_elementwise_max(x, y));
}
__device__ __forceinline__ uint4 shflx4(uint4 a, int off){
  uint4 r;
  r.x = (uint)__shfl_xor((int)a.x, off, 64);
  r.y = (uint)__shfl_xor((int)a.y, off, 64);
  r.z = (uint)__shfl_xor((int)a.z, off, 64);
  r.w = (uint)__shfl_xor((int)a.w, off, 64);
  return r;
}
__device__ __forceinline__ f32x2 b2lo(uint u){
  f32x2 r; r.x = lo16(u); r.y = hi16(u); return r;
}

// ---------------- weight prep + dtype detect + counter zero ----------------
struct WConv {
  const void* src[13];
  int n[13], isbias[13], Cs[13], K[13], off[13];
};

__global__ void conv_w(WConv wc, unsigned short* wtbase, float* bbase,
                       const unsigned short* x, const int* ei,
                       int* flags, int* ccur, int NB){
  __shared__ int sflags[2];
  int t = threadIdx.x;
  if (t < 64){
    int sane = 0;
    #pragma unroll
    for (int k = 0; k < 4; ++k){
      int e = (x[(t * 4 + k) * 2] >> 7) & 0xff;
      sane += (e >= 118 && e <= 134);
    }
    #pragma unroll
    for (int off = 32; off; off >>= 1) sane += __shfl_down(sane, off, 64);
    unsigned long long b = __ballot(ei[1 + 2 * t] != 0);
    if (t == 0){ sflags[0] = (sane >= 128); sflags[1] = (b == 0ull); }
  }
  __syncthreads();
  int isbf = sflags[0];
  if (blockIdx.x == 0){
    if (t == 0){ flags[0] = sflags[0]; flags[1] = sflags[1]; }
    for (int i = t; i < NB; i += 256) ccur[i] = 0;
  }
  int bt = blockIdx.x, n = wc.n[bt];
  if (wc.isbias[bt]){
    float* d = bbase + wc.off[bt];
    for (int i = t; i < n; i += 256)
      d[i] = isbf ? bf2f(((const unsigned short*)wc.src[bt])[i])
                  : ((const float*)wc.src[bt])[i];
  } else {
    unsigned short* d = wtbase + wc.off[bt];
    int Cs = wc.Cs[bt], K = wc.K[bt], Cm = (1 << Cs) - 1;
    for (int i = t; i < n; i += 256){
      int k = i >> Cs, c = i & Cm;
      unsigned short v = isbf ? ((const unsigned short*)wc.src[bt])[i]
                              : f2bf(((const float*)wc.src[bt])[i]);
      d[c * K + k] = v;
    }
  }
}

__device__ __forceinline__ void load_edge(const void* ei, int E, int is64, int e,
                                          int& s, int& d){
  if (is64){
    const long long* p = (const long long*)ei;
    s = (int)p[e]; d = (int)p[E + e];
  } else {
    const int* p = (const int*)ei;
    s = p[e]; d = p[E + e];
  }
}

// ---------------- MFMA helpers ----------------
__device__ __forceinline__ short8 ld_fragA_bf16(const unsigned short* A, int row,
                                                int K, int koff){
  return *(const short8*)(A + (size_t)row * K + koff);
}
__device__ __forceinline__ short8 ld_fragA_f32(const float* A, int row,
                                               int K, int koff){
  const float* q = A + (size_t)row * K + koff;
  float4 f0 = *(const float4*)q;
  float4 f1 = *(const float4*)(q + 4);
  short8 r;
  r[0] = (short)f2bf(f0.x); r[1] = (short)f2bf(f0.y);
  r[2] = (short)f2bf(f0.z); r[3] = (short)f2bf(f0.w);
  r[4] = (short)f2bf(f1.x); r[5] = (short)f2bf(f1.y);
  r[6] = (short)f2bf(f1.z); r[7] = (short)f2bf(f1.w);
  return r;
}
// relu bf16 with -0.0 (0x8000) squashed so packed-u16 max stays exact.
__device__ __forceinline__ unsigned short f2bf_relu(float f){
  return (unsigned short)(f2bf(fmaxf(f, 0.f)) & 0x7fff);
}

// ---------------- hybrid: CSR phase1 (blocks < nP) || mm1 (rest) ------------
#define CSR_CE 8192

// two-pass multisplit (pass 2 re-reads slab from XCD L2).
__device__ __forceinline__ void phase1_body(
    const void* __restrict__ ei, const int* __restrict__ flags,
    int* __restrict__ ccur, uint* __restrict__ pairs,
    int E, int N, int NB, int S, int CAP, int blk,
    uint* hist, uint* gbase)
{
  int t = threadIdx.x;
  uint dmask = (1u << S) - 1u;
  int is64 = flags[1];
  int e0 = blk * CSR_CE;
  for (int i = t; i < 1024; i += 256) hist[i] = 0;
  __syncthreads();
  #pragma unroll 4
  for (int it = 0; it < CSR_CE / 256; ++it){
    int e = e0 + it * 256 + t;
    if (e >= E) break;
    int s, d; load_edge(ei, E, is64, e, s, d);
    if ((unsigned)s >= (unsigned)N || (unsigned)d >= (unsigned)N) continue;
    atomicAdd(&hist[d >> S], 1u);
  }
  __syncthreads();
  for (int b = t; b < NB; b += 256){
    uint c = hist[b];
    if (c) gbase[b] = (uint)atomicAdd(&ccur[b], (int)c);
    hist[b] = 0;
  }
  __syncthreads();
  #pragma unroll 4
  for (int it = 0; it < CSR_CE / 256; ++it){
    int e = e0 + it * 256 + t;
    if (e >= E) break;
    int s, d; load_edge(ei, E, is64, e, s, d);
    if ((unsigned)s >= (unsigned)N || (unsigned)d >= (unsigned)N) continue;
    int b = d >> S;
    uint local = atomicAdd(&hist[b], 1u);
    uint pos = gbase[b] + local;
    if (pos >= (uint)CAP) pos = (uint)CAP - 1;   // pathological-skew guard
    pairs[(size_t)b * CAP + pos] = ((uint)s << S) | ((uint)d & dmask);
  }
}

// mm1: mbuf = relu(x@W1p + b1p). 2 row-tiles per wave (32 rows/block, C=64).
template<int AMODE>
__device__ __forceinline__ void mm1_body(
    const void* __restrict__ Av, const unsigned short* __restrict__ WaT,
    const float* __restrict__ bias, const int* __restrict__ flags,
    unsigned short* __restrict__ out, int N, int blk)
{
  int wid = threadIdx.x >> 6, lane = threadIdx.x & 63;
  int n0 = blk * 32;
  int m = lane & 15, quad = lane >> 4, koq = quad * 8;
  int colbase = wid * 16;
  int rowc0 = min(n0 + m, N - 1);
  int rowc1 = min(n0 + 16 + m, N - 1);
  bool af32 = (AMODE == 2) && (flags[0] == 0);
  f32x4 a0 = {0.f,0.f,0.f,0.f}, a1 = {0.f,0.f,0.f,0.f};
  #pragma unroll
  for (int k0 = 0; k0 < 64; k0 += 32){
    short8 af0 = af32 ? ld_fragA_f32((const float*)Av, rowc0, 64, k0 + koq)
                      : ld_fragA_bf16((const unsigned short*)Av, rowc0, 64, k0 + koq);
    short8 af1 = af32 ? ld_fragA_f32((const float*)Av, rowc1, 64, k0 + koq)
                      : ld_fragA_bf16((const unsigned short*)Av, rowc1, 64, k0 + koq);
    short8 wf = *(const short8*)(WaT + (size_t)(colbase + m) * 64 + k0 + koq);
    a0 = __builtin_amdgcn_mfma_f32_16x16x32_bf16(af0, wf, a0, 0, 0, 0);
    a1 = __builtin_amdgcn_mfma_f32_16x16x32_bf16(af1, wf, a1, 0, 0, 0);
  }
  float bv = bias[colbase + m];
  #pragma unroll
  for (int r = 0; r < 4; ++r){
    int rl = quad * 4 + r;
    if (n0 + rl < N)
      out[(size_t)(n0 + rl) * 64 + colbase + m] = f2bf_relu(a0[r] + bv);
    if (n0 + 16 + rl < N)
      out[(size_t)(n0 + 16 + rl) * 64 + colbase + m] = f2bf_relu(a1[r] + bv);
  }
}

template<int AMODE>
__global__ __launch_bounds__(256) void phase1_mm1(
    const void* __restrict__ ei, const int* __restrict__ flags,
    int* __restrict__ ccur, uint* __restrict__ pairs,
    int E, int N, int NB, int S, int CAP, int nP,
    const void* __restrict__ x, const unsigned short* __restrict__ W1pT,
    const float* __restrict__ b1p, unsigned short* __restrict__ mbuf)
{
  __shared__ uint hist[1024];
  __shared__ uint gbase[1024];
  if ((int)blockIdx.x < nP)
    phase1_body(ei, flags, ccur, pairs, E, N, NB, S, CAP, blockIdx.x, hist, gbase);
  else
    mm1_body<AMODE>(x, W1pT, b1p, flags, mbuf, N, blockIdx.x - nP);
}

// scan of final counts -> cbase[0..NB] (+ row_ptr[N] = total).
__global__ void csr_scan0(const int* __restrict__ ccur, int* __restrict__ cbase,
                          int* __restrict__ rowptrN, int NB, int CAP)
{
  __shared__ int sm[256];
  int t = threadIdx.x;
  int g = (NB + 255) / 256;          // <= 4
  int vb = t * g, v[4], s = 0;
  for (int k = 0; k < g; ++k){
    int i = vb + k; int x = (i < NB) ? min(ccur[i], CAP) : 0; v[k] = x; s += x;
  }
  sm[t] = s; __syncthreads();
  for (int off = 1; off < 256; off <<= 1){
    int x = (t >= off) ? sm[t - off] : 0;
    __syncthreads(); sm[t] += x; __syncthreads();
  }
  int run = sm[t] - s;
  for (int k = 0; k < g; ++k){
    int i = vb + k;
    if (i < NB){ cbase[i] = run; run += v[k]; }
  }
  if (t == 255){ cbase[NB] = run; *rowptrN = run; }
}

// phase2: per-bucket hist+scan in LDS -> row_ptr slice, exact placement.
#define P2_CAP 6144
__global__ __launch_bounds__(256) void csr_phase2(
    const int* __restrict__ cbase, const int* __restrict__ ccur,
    const uint* __restrict__ pairs,
    int* __restrict__ bucket, int* __restrict__ row_ptr, int N, int S, int CAP)
{
  __shared__ int lbuf[P2_CAP];
  __shared__ int cur[1024];
  __shared__ int sm[256];
  int b = blockIdx.x, t = threadIdx.x;
  uint dmask = (1u << S) - 1u;
  int n0 = b << S;
  int n1 = n0 + (1 << S); if (n1 > N) n1 = N;
  int nn = n1 - n0;
  int base = cbase[b];
  int cnt = min(ccur[b], CAP);
  const uint* bp = pairs + (size_t)b * CAP;

  for (int i = t; i < nn; i += 256) cur[i] = 0;
  __syncthreads();
  for (int j = t; j < cnt; j += 256)
    atomicAdd(&cur[(int)(bp[j] & dmask)], 1);
  __syncthreads();
  int g = (nn + 255) / 256, vb = t * g, v[4], s = 0;
  for (int k = 0; k < g; ++k){
    int i = vb + k; int x = (i < nn) ? cur[i] : 0; v[k] = x; s += x;
  }
  sm[t] = s; __syncthreads();
  for (int off = 1; off < 256; off <<= 1){
    int x = (t >= off) ? sm[t - off] : 0;
    __syncthreads(); sm[t] += x; __syncthreads();
  }
  int run = sm[t] - s;
  for (int k = 0; k < g; ++k){
    int i = vb + k;
    if (i < nn){ row_ptr[n0 + i] = base + run; cur[i] = run; run += v[k]; }
  }
  __syncthreads();
  if (cnt <= 0) return;
  if (cnt <= P2_CAP){
    for (int j = t; j < cnt; j += 256){
      uint pr = bp[j];
      int pos = atomicAdd(&cur[(int)(pr & dmask)], 1);
      lbuf[pos] = (int)(pr >> S);
    }
    __syncthreads();
    for (int i = t; i < cnt; i += 256) bucket[base + i] = lbuf[i];
  } else {
    for (int j = t; j < cnt; j += 256){
      uint pr = bp[j];
      int pos = atomicAdd(&cur[(int)(pr & dmask)], 1);
      bucket[base + pos] = (int)(pr >> S);
    }
  }
}

// ---------------- max-gather pair -> LDS rows (device fn, R9 core) ----------
__device__ __forceinline__ void gmax_pair(
    const int* __restrict__ row_ptr, const int* __restrict__ bucket,
    const unsigned short* __restrict__ m,
    unsigned short* la_row, int LDH, int nodeA, int N, int lane)
{
  int nodeB = nodeA + 1;
  int nAc = min(nodeA, N - 1);
  int rsA = row_ptr[nAc], reA = row_ptr[nAc + 1];
  int cntA = (nodeA < N) ? (reA - rsA) : 0;
  int rsB = reA;
  int cntB = (nodeB < N) ? (row_ptr[nodeB + 1] - reA) : 0;
  int fg8 = (lane & 7) * 8, rowsel = lane >> 3;
  uint4 accA = {0u,0u,0u,0u}, accB = {0u,0u,0u,0u};
  int cmax = max(cntA, cntB);
  for (int c0 = 0; c0 < cmax; c0 += 64){
    int chA = min(cntA - c0, 64);
    int chB = min(cntB - c0, 64);
    int bvA = (lane < chA) ? bucket[rsA + c0 + lane] : 0;
    int bvB = (lane < chB) ? bucket[rsB + c0 + lane] : 0;
    int it = (max(chA, chB) + 7) >> 3;
    for (int k = 0; k < it; ++k){
      int j = k * 8 + rowsel;
      int sA = __shfl(bvA, j, 64);
      int sB = __shfl(bvB, j, 64);
      uint4 vA = *(const uint4*)(m + (size_t)sA * 64 + fg8);
      uint4 vB = *(const uint4*)(m + (size_t)sB * 64 + fg8);
      if (j < chA) accA = pkmax4(accA, vA);
      if (j < chB) accB = pkmax4(accB, vB);
    }
  }
  #pragma unroll
  for (int off = 8; off <= 32; off <<= 1){
    accA = pkmax4(accA, shflx4(accA, off));
    accB = pkmax4(accB, shflx4(accB, off));
  }
  if (lane < 8){
    *(uint4*)(la_row + fg8) = accA;
  } else if (lane < 16){
    *(uint4*)(la_row + LDH + (lane & 7) * 8) = accB;
  }
}

// ---------------- layer 1 fused: gather1 + (x@W1s + agg@W1n) + m2 -----------
// Block = 32 rows. Stage A: 4 waves gather 8 nodes each into la (LDS).
// Stage B: h1 = relu(x@W1s + la@W1n + b1) -> hl (LDS) + out1. Stage C:
// m2 = relu(hl@W2p + b2p) -> out2 (separate buffer: m1 still being read).
template<int AMODE>
__global__ __launch_bounds__(256) void gmax_mm_fused(
    const void* __restrict__ Av, const unsigned short* __restrict__ msrc,
    const int* __restrict__ row_ptr, const int* __restrict__ bucket,
    const unsigned short* __restrict__ WaT, const unsigned short* __restrict__ WbT,
    const float* __restrict__ bias1,
    const unsigned short* __restrict__ WcT, const float* __restrict__ bias2,
    const int* __restrict__ flags,
    unsigned short* __restrict__ out1, unsigned short* __restrict__ out2, int N)
{
  constexpr int K = 64, C = 64, LDH = 72;
  __shared__ unsigned short la[32 * LDH];
  __shared__ unsigned short hl[32 * LDH];
  int wid = threadIdx.x >> 6, lane = threadIdx.x & 63;
  int n0 = blockIdx.x * 32;
  #pragma unroll
  for (int p = 0; p < 4; ++p){
    int lr = wid * 8 + p * 2;
    gmax_pair(row_ptr, bucket, msrc, la + (size_t)lr * LDH, LDH, n0 + lr, N, lane);
  }
  __syncthreads();
  int m = lane & 15, quad = lane >> 4, koq = quad * 8;
  int colbase = wid * 16;
  int rowc0 = min(n0 + m, N - 1);
  int rowc1 = min(n0 + 16 + m, N - 1);
  bool af32 = (AMODE == 2) && (flags[0] == 0);

  f32x4 a0 = {0.f,0.f,0.f,0.f}, a1 = {0.f,0.f,0.f,0.f};
  #pragma unroll
  for (int k0 = 0; k0 < K; k0 += 32){
    short8 af0 = af32 ? ld_fragA_f32((const float*)Av, rowc0, K, k0 + koq)
                      : ld_fragA_bf16((const unsigned short*)Av, rowc0, K, k0 + koq);
    short8 af1 = af32 ? ld_fragA_f32((const float*)Av, rowc1, K, k0 + koq)
                      : ld_fragA_bf16((const unsigned short*)Av, rowc1, K, k0 + koq);
    short8 wf = *(const short8*)(WaT + (size_t)(colbase + m) * K + k0 + koq);
    a0 = __builtin_amdgcn_mfma_f32_16x16x32_bf16(af0, wf, a0, 0, 0, 0);
    a1 = __builtin_amdgcn_mfma_f32_16x16x32_bf16(af1, wf, a1, 0, 0, 0);
    short8 bf0 = *(const short8*)(la + m * LDH + k0 + koq);
    short8 bf1 = *(const short8*)(la + (16 + m) * LDH + k0 + koq);
    short8 wg = *(const short8*)(WbT + (size_t)(colbase + m) * K + k0 + koq);
    a0 = __builtin_amdgcn_mfma_f32_16x16x32_bf16(bf0, wg, a0, 0, 0, 0);
    a1 = __builtin_amdgcn_mfma_f32_16x16x32_bf16(bf1, wg, a1, 0, 0, 0);
  }
  float bv = bias1[colbase + m];
  #pragma unroll
  for (int r = 0; r < 4; ++r){
    int rl = quad * 4 + r;
    unsigned short h0 = f2bf_relu(a0[r] + bv);
    unsigned short h1v = f2bf_relu(a1[r] + bv);
    hl[rl * LDH + colbase + m] = h0;
    hl[(16 + rl) * LDH + colbase + m] = h1v;
    if (n0 + rl < N) out1[(size_t)(n0 + rl) * C + colbase + m] = h0;
    if (n0 + 16 + rl < N) out1[(size_t)(n0 + 16 + rl) * C + colbase + m] = h1v;
  }
  __syncthreads();
  f32x4 c0 = {0.f,0.f,0.f,0.f}, c1 = {0.f,0.f,0.f,0.f};
  #pragma unroll
  for (int k0 = 0; k0 < K; k0 += 32){
    short8 q0 = *(const short8*)(hl + m * LDH + k0 + koq);
    short8 q1 = *(const short8*)(hl + (16 + m) * LDH + k0 + koq);
    short8 wf = *(const short8*)(WcT + (size_t)(colbase + m) * K + k0 + koq);
    c0 = __builtin_amdgcn_mfma_f32_16x16x32_bf16(q0, wf, c0, 0, 0, 0);
    c1 = __builtin_amdgcn_mfma_f32_16x16x32_bf16(q1, wf, c1, 0, 0, 0);
  }
  float b2v = bias2[colbase + m];
  #pragma unroll
  for (int r = 0; r < 4; ++r){
    int rl = quad * 4 + r;
    if (n0 + rl < N)
      out2[(size_t)(n0 + rl) * C + colbase + m] = f2bf_relu(c0[r] + b2v);
    if (n0 + 16 + rl < N)
      out2[(size_t)(n0 + 16 + rl) * C + colbase + m] = f2bf_relu(c1[r] + b2v);
  }
}

// ---------------- layer 2 fused: gather2 + (h1@W2s + agg@W2n) ----------------
// Block = 64 rows: 4 waves gather 16 nodes each into la, then MM (C=32).
__global__ __launch_bounds__(256) void gmax_mm2(
    const unsigned short* __restrict__ h1, const unsigned short* __restrict__ msrc,
    const int* __restrict__ row_ptr, const int* __restrict__ bucket,
    const unsigned short* __restrict__ WsT, const unsigned short* __restrict__ WnT,
    const float* __restrict__ bias, unsigned short* __restrict__ h2, int N)
{
  constexpr int LDH = 72;
  __shared__ unsigned short la[64 * LDH];
  int wid = threadIdx.x >> 6, lane = threadIdx.x & 63;
  int n0 = blockIdx.x * 64;
  #pragma unroll
  for (int p = 0; p < 8; ++p){
    int lr = wid * 16 + p * 2;
    gmax_pair(row_ptr, bucket, msrc, la + (size_t)lr * LDH, LDH, n0 + lr, N, lane);
  }
  __syncthreads();
  int m = lane & 15, quad = lane >> 4, koq = quad * 8;
  int colbase = (wid & 1) * 16;
  int rb = (wid >> 1) * 32;
  int rowc0 = min(n0 + rb + m, N - 1), rowc1 = min(n0 + rb + 16 + m, N - 1);
  f32x4 a0 = {0.f,0.f,0.f,0.f}, a1 = {0.f,0.f,0.f,0.f};
  #pragma unroll
  for (int k0 = 0; k0 < 64; k0 += 32){
    short8 af0 = *(const short8*)(h1 + (size_t)rowc0 * 64 + k0 + koq);
    short8 af1 = *(const short8*)(h1 + (size_t)rowc1 * 64 + k0 + koq);
    short8 wf = *(const short8*)(WsT + (size_t)(colbase + m) * 64 + k0 + koq);
    a0 = __builtin_amdgcn_mfma_f32_16x16x32_bf16(af0, wf, a0, 0, 0, 0);
    a1 = __builtin_amdgcn_mfma_f32_16x16x32_bf16(af1, wf, a1, 0, 0, 0);
    short8 bf0 = *(const short8*)(la + (rb + m) * LDH + k0 + koq);
    short8 bf1 = *(const short8*)(la + (rb + 16 + m) * LDH + k0 + koq);
    short8 wg = *(const short8*)(WnT + (size_t)(colbase + m) * 64 + k0 + koq);
    a0 = __builtin_amdgcn_mfma_f32_16x16x32_bf16(bf0, wg, a0, 0, 0, 0);
    a1 = __builtin_amdgcn_mfma_f32_16x16x32_bf16(bf1, wg, a1, 0, 0, 0);
  }
  float bv = bias[colbase + m];
  #pragma unroll
  for (int r = 0; r < 4; ++r){
    int rl = quad * 4 + r;
    if (n0 + rb + rl < N)
      h2[(size_t)(n0 + rb + rl) * 32 + colbase + m] = f2bf(a0[r] + bv);
    if (n0 + rb + 16 + rl < N)
      h2[(size_t)(n0 + rb + 16 + rl) * 32 + colbase + m] = f2bf(a1[r] + bv);
  }
}

// Fused layer 3: mean-gather (block = 16 nodes) -> LDS agg tile -> MFMA.
__global__ __launch_bounds__(256) void gsum3(
    const int* __restrict__ row_ptr, const int* __restrict__ bucket,
    const unsigned short* __restrict__ h2,
    const unsigned short* __restrict__ W3sT, const unsigned short* __restrict__ W3nT,
    const float* __restrict__ b3, float* __restrict__ out, int N)
{
  constexpr int LDA = 40;
  __shared__ unsigned short la[16 * LDA];
  int t = threadIdx.x;
  int w = t >> 6, lane = t & 63;
  int n0 = blockIdx.x * 16;
  int g = lane >> 4, q = lane & 15;
  int nd = n0 + w * 4 + g;
  int ndc = nd < N ? nd : N - 1;
  int rs = row_ptr[ndc];
  int cnt = (nd < N) ? (row_ptr[ndc + 1] - rs) : 0;
  int fg8 = (q & 3) * 8, rowsel = q >> 2;
  f32x2 a0 = {0.f,0.f}, a1 = {0.f,0.f}, a2 = {0.f,0.f}, a3 = {0.f,0.f};
  for (int c0 = 0; c0 < cnt; c0 += 16){
    int chunk = min(cnt - c0, 16);
    int bval = (q < chunk) ? bucket[rs + c0 + q] : 0;
    int it = (chunk + 3) >> 2;
    for (int k = 0; k < it; ++k){
      int j = k * 4 + rowsel;
      int s = __shfl(bval, (g << 4) + j, 64);
      uint4 v = *(const uint4*)(h2 + (size_t)s * 32 + fg8);
      if (j < chunk){
        a0 += b2lo(v.x); a1 += b2lo(v.y); a2 += b2lo(v.z); a3 += b2lo(v.w);
      }
    }
  }
  #pragma unroll
  for (int off = 4; off <= 8; off <<= 1){
    a0.x += __shfl_xor(a0.x, off, 64); a0.y += __shfl_xor(a0.y, off, 64);
    a1.x += __shfl_xor(a1.x, off, 64); a1.y += __shfl_xor(a1.y, off, 64);
    a2.x += __shfl_xor(a2.x, off, 64); a2.y += __shfl_xor(a2.y, off, 64);
    a3.x += __shfl_xor(a3.x, off, 64); a3.y += __shfl_xor(a3.y, off, 64);
  }
  if (rowsel == 0){
    float sc = 1.f / fmaxf((float)cnt, 1.f);
    int r = w * 4 + g;
    uint4 pk;
    pk.x = (uint)f2bf(a0.x * sc) | ((uint)f2bf(a0.y * sc) << 16);
    pk.y = (uint)f2bf(a1.x * sc) | ((uint)f2bf(a1.y * sc) << 16);
    pk.z = (uint)f2bf(a2.x * sc) | ((uint)f2bf(a2.y * sc) << 16);
    pk.w = (uint)f2bf(a3.x * sc) | ((uint)f2bf(a3.y * sc) << 16);
    *(uint4*)(la + r * LDA + q * 8) = pk;
  }
  __syncthreads();
  if (w < 2){
    int m = lane & 15, quad = lane >> 4, koq = quad * 8;
    int colbase = w * 16;
    int row = n0 + m;
    int rowc = row < N ? row : N - 1;
    f32x4 acc = {0.f, 0.f, 0.f, 0.f};
    short8 aself = *(const short8*)(h2 + (size_t)rowc * 32 + koq);
    short8 wfs = *(const short8*)(W3sT + (size_t)(colbase + m) * 32 + koq);
    acc = __builtin_amdgcn_mfma_f32_16x16x32_bf16(aself, wfs, acc, 0, 0, 0);
    short8 aagg = *(const short8*)(la + m * LDA + koq);
    short8 wfn = *(const short8*)(W3nT + (size_t)(colbase + m) * 32 + koq);
    acc = __builtin_amdgcn_mfma_f32_16x16x32_bf16(aagg, wfn, acc, 0, 0, 0);
    float bv = b3[colbase + m];
    #pragma unroll
    for (int r = 0; r < 4; ++r){
      int orow = n0 + quad * 4 + r;
      if (orow < N) out[(size_t)orow * 32 + colbase + m] = acc[r] + bv;
    }
  }
}

static inline char* align256(char* p){
  return (char*)(((uintptr_t)p + 255) & ~(uintptr_t)255);
}

extern "C" void kernel_launch(void* const* d_in, const int* in_sizes, int n_in,
                              void* d_out, int out_size, void* d_ws, size_t ws_size,
                              hipStream_t stream)
{
  const void* x = d_in[0];
  const void* ei = d_in[1];
  int N = in_sizes[0] / 64;   // 100000
  int E = in_sizes[1] / 2;    // 1600000

  char* ws = (char*)d_ws;
  unsigned short* wtbase = (unsigned short*)ws;     // 22528 ushorts (45KB)
  float* bbase = (float*)(ws + 65536);              // 256 floats
  int* flags = (int*)(ws + 131072 - 256);

  int S = 7, NB = (N + 127) >> 7;
  while (NB > 1024){ S++; NB = (N + (1 << S) - 1) >> S; }
  int CAP = ((2 * E / NB) + 255) & ~255;
  if (CAP < 1024) CAP = 1024;

  char* p = ws + 131072;
  int* row_ptr = (int*)p; p = align256(p + (size_t)(N + 1) * 4);
  int* cbase   = (int*)p; p = align256(p + 4352);
  int* ccur    = (int*)p; p = align256(p + 4352);
  int* bucket  = (int*)p; p = align256(p + (size_t)E * 4);
  uint* pairs  = (uint*)p; p = align256(p + (size_t)NB * CAP * 4);
  char* P = p;  p = align256(p + (size_t)N * 64 * 2);   // m1, later h2
  char* Q = p;  p = align256(p + (size_t)N * 64 * 2);   // m2
  char* R = p;  p = align256(p + (size_t)N * 64 * 2);   // h1
  unsigned short* m1 = (unsigned short*)P;
  unsigned short* h2 = (unsigned short*)P;   // after m1 dead (layer2 writes)
  unsigned short* m2 = (unsigned short*)Q;
  unsigned short* h1 = (unsigned short*)R;

  WConv wc;
  {
    const int widx[13] = {2, 3, 4, 5, 6, 7, 8, 9, 10, 11, 12, 13, 14};
    const int isb[13]  = {0, 1, 0, 0, 1, 0, 1, 0, 0, 1, 0, 0, 1};
    const int Cs[13]   = {6, 0, 6, 6, 0, 6, 0, 5, 5, 0, 5, 5, 0};
    const int Kk[13]   = {64, 0, 64, 64, 0, 64, 0, 64, 64, 0, 32, 32, 0};
    const int off[13]  = {0, 0, 4096, 8192, 64, 12288, 128, 16384, 18432, 192,
                          20480, 21504, 224};
    for (int i = 0; i < 13; ++i){
      wc.src[i] = d_in[widx[i]]; wc.n[i] = in_sizes[widx[i]];
      wc.isbias[i] = isb[i]; wc.Cs[i] = Cs[i]; wc.K[i] = Kk[i]; wc.off[i] = off[i];
    }
  }
  hipLaunchKernelGGL(conv_w, dim3(13), dim3(256), 0, stream, wc, wtbase, bbase,
                     (const unsigned short*)x, (const int*)ei, flags, ccur, NB);
  unsigned short* W1pT = wtbase + 0;     unsigned short* W1sT = wtbase + 4096;
  unsigned short* W1nT = wtbase + 8192;  unsigned short* W2pT = wtbase + 12288;
  unsigned short* W2sT = wtbase + 16384; unsigned short* W2nT = wtbase + 18432;
  unsigned short* W3sT = wtbase + 20480; unsigned short* W3nT = wtbase + 21504;
  float* b1p = bbase + 0;  float* b1 = bbase + 64; float* b2p = bbase + 128;
  float* b2 = bbase + 192; float* b3 = bbase + 224;

  int nP = (E + CSR_CE - 1) / CSR_CE;
  int RT32 = (N + 31) / 32;
  int RT16 = (N + 15) / 16;

  // ---- hybrid: CSR phase1 || mm1 (independent work, one grid) ----
  phase1_mm1<2><<<nP + RT32, 256, 0, stream>>>(
      ei, flags, ccur, pairs, E, N, NB, S, CAP, nP, x, W1pT, b1p, m1);
  csr_scan0<<<1, 256, 0, stream>>>(ccur, cbase, row_ptr + N, NB, CAP);
  csr_phase2<<<NB, 256, 0, stream>>>(cbase, ccur, pairs, bucket, row_ptr, N, S, CAP);

  // ---- layer 1 fused: gather1 + h1 + m2 (m2 -> Q: m1 still live) ----
  gmax_mm_fused<2><<<RT32,256,0,stream>>>(
      x, m1, row_ptr, bucket, W1sT, W1nT, b1, W2pT, b2p, flags, h1, m2, N);

  // ---- layer 2 fused: gather2 + h2 (h2 -> P: m1 dead now) ----
  gmax_mm2<<<(N + 63) / 64,256,0,stream>>>(
      h1, m2, row_ptr, bucket, W2sT, W2nT, b2, h2, N);

  // ---- layer 3 fused (mean-gather + MFMA, f32 out) ----
  gsum3<<<RT16,256,0,stream>>>(row_ptr, bucket, h2, W3sT, W3nT, b3,
                               (float*)d_out, N);
}